// Round 10
// baseline (381.942 us; speedup 1.0000x reference)
//
#include <hip/hip_runtime.h>
#include <stdint.h>

// ---------------------------------------------------------------------------
// NonLocalBlockND: B=8, C_IN=256, C_INTER=128, H=W=128, P=16 -> tokens 256/batch,
// token dim D = 128*64 = 8192 (d = c*64 + s, s = u*8+v within 8x8 patch).
// Pipeline:
//   K1 prep   : weights -> bf16 (A-fragment swizzled, hi/lo split) + zero stats
//   K2 proj   : TWO tokens/block (grid 1024, 512 thr, XCD batch-chunked);
//               x staged hi/lo in 128KB dynamic LDS; 8 waves each own a
//               16-wide o-slice -> 5 weight frags per kk feed 16 MFMAs.
//   K3 qk     : f = theta . phi (3-term bf16 split MFMA), K-split 16; XCD-chunk
//               swizzle puts the 4 (mt,nt) siblings of each (b,kc) on ONE XCD
//               back-to-back -> shared theta/phi slice is an L2 hit.
//   K4 softmax: reduce partials, softmax rows -> p (bf16)
//   K5 pv     : y = p . g; nt-fastest decode + XCD-chunk swizzle -> 4 nt
//               siblings share the g slice in L2. g staged transposed (b128).
//   K6 wconv  : w_y = y . w_w + w_b; y staged transposed -> b128 fragment reads
//   K7 final  : out = (w_y - mean)*rsqrt(var+eps)*gamma + beta + x   (fp32)
// ---------------------------------------------------------------------------

typedef unsigned short u16t;
typedef short s16x8 __attribute__((ext_vector_type(8)));
typedef float f32x4 __attribute__((ext_vector_type(4)));
typedef uint32_t u32x4 __attribute__((ext_vector_type(4)));

#define DEV __device__ __forceinline__

DEV u16t f2bf(float f) {
    union { float f; uint32_t u; } v; v.f = f;
    return (u16t)((v.u + 0x7FFFu + ((v.u >> 16) & 1u)) >> 16);
}
DEV float bf2f(u16t h) {
    union { uint32_t u; float f; } v; v.u = ((uint32_t)h) << 16; return v.f;
}
DEV f32x4 MFMA(s16x8 a, s16x8 b, f32x4 c) {
    return __builtin_amdgcn_mfma_f32_16x16x32_bf16(a, b, c, 0, 0, 0);
}

// ---------------- K1: weight prep -> bf16 + stats zero -----------------------
__global__ void __launch_bounds__(256) k_prep(
    const float* __restrict__ gw, const float* __restrict__ tw,
    const float* __restrict__ pw, const float* __restrict__ ww,
    u16t* __restrict__ wb, float* __restrict__ stats)
{
    int i = blockIdx.x * 256 + threadIdx.x;
    if (blockIdx.x == 0) {
        stats[threadIdx.x] = 0.f;
        stats[256 + threadIdx.x] = 0.f;
    }
    if (i >= 32768) return;
    int o = i >> 8, c = i & 255;
    int fi = ((o >> 4) * 8 + (c >> 5)) * 512 + (((c >> 3) & 3) * 16 + (o & 15)) * 8 + (c & 7);
    float t = tw[i], p = pw[i];
    u16t th = f2bf(t); u16t tl = f2bf(t - bf2f(th));
    u16t ph = f2bf(p); u16t pl = f2bf(p - bf2f(ph));
    wb[fi] = th; wb[32768 + fi] = tl;
    wb[65536 + fi] = ph; wb[98304 + fi] = pl;
    wb[131072 + fi] = f2bf(gw[i]);
    wb[163840 + i] = f2bf(ww[i]);
}

// ---------------- K2: projections, 2 tokens/block, o-slice-16 waves ----------
__global__ void __launch_bounds__(512, 2) k_proj(
    const float* __restrict__ x, const u16t* __restrict__ wb,
    const float* __restrict__ tb, const float* __restrict__ pb, const float* __restrict__ gbias,
    float* __restrict__ out_t, float* __restrict__ out_p, u16t* __restrict__ out_g)
{
    extern __shared__ u16t smem[];           // xh[2][64][256] | xl[2][64][256] = 128KB
    u16t* xh = smem;
    u16t* xl = smem + 32768;
    int phys = blockIdx.x;
    int blk = ((phys & 7) << 7) | (phys >> 3);   // XCD chunking: one batch per XCD
    int b = blk >> 7, n0 = (blk & 127) * 2;      // token pair (pj-adjacent)
    int t = threadIdx.x;
    int w = t >> 6, l = t & 63, lr = l & 15, lg = l >> 4;

    // ---- stage x hi/lo: lane = pixel, wave (w&3) covers octets [8(w&3), +8)
    {
        int tok = w >> 2, wq = w & 3, p = l;
        int n = n0 + tok;
        int pi = n >> 4, pj = n & 15;
        const float* xb = x + (((size_t)b * 256) * 128 + pi * 8 + (p >> 3)) * 128 + pj * 8 + (p & 7);
        u16t* dh = xh + tok * 16384;
        u16t* dl = xl + tok * 16384;
#pragma unroll
        for (int i = 0; i < 8; ++i) {
            int octet = wq * 8 + i;
            float v[8];
#pragma unroll
            for (int j = 0; j < 8; ++j) v[j] = xb[(size_t)(octet * 8 + j) * 16384];
            u32x4 hv, lv;
#pragma unroll
            for (int j = 0; j < 8; j += 2) {
                uint32_t u0 = __float_as_uint(v[j]), u1 = __float_as_uint(v[j + 1]);
                hv[j >> 1] = (u0 >> 16) | (u1 & 0xFFFF0000u);          // truncation hi
                float f0 = v[j]     - __uint_as_float(u0 & 0xFFFF0000u);
                float f1 = v[j + 1] - __uint_as_float(u1 & 0xFFFF0000u);
                lv[j >> 1] = (uint32_t)f2bf(f0) | ((uint32_t)f2bf(f1) << 16);  // RN lo
            }
            int oct2 = (octet + p) & 31;
            *(s16x8*)(dh + p * 256 + oct2 * 8) = __builtin_bit_cast(s16x8, hv);
            *(s16x8*)(dl + p * 256 + oct2 * 8) = __builtin_bit_cast(s16x8, lv);
        }
    }
    __syncthreads();

    f32x4 aT[2][4], aP[2][4], aG[2][4];
#pragma unroll
    for (int tok = 0; tok < 2; ++tok)
#pragma unroll
        for (int ct = 0; ct < 4; ++ct) {
            aT[tok][ct] = (f32x4){0.f, 0.f, 0.f, 0.f};
            aP[tok][ct] = (f32x4){0.f, 0.f, 0.f, 0.f};
            aG[tok][ct] = (f32x4){0.f, 0.f, 0.f, 0.f};
        }

#pragma unroll
    for (int kk = 0; kk < 8; ++kk) {
        size_t off = (size_t)((w * 8 + kk) * 64 + l) * 8;
        s16x8 th_ = *(const s16x8*)(wb + off);
        s16x8 tl_ = *(const s16x8*)(wb + 32768 + off);
        s16x8 ph_ = *(const s16x8*)(wb + 65536 + off);
        s16x8 pl_ = *(const s16x8*)(wb + 98304 + off);
        s16x8 gh_ = *(const s16x8*)(wb + 131072 + off);
#pragma unroll
        for (int ct = 0; ct < 4; ++ct) {
            int pr = ct * 16 + lr;
            int rot = (kk * 4 + lg + pr) & 31;
#pragma unroll
            for (int tok = 0; tok < 2; ++tok) {
                const u16t* bp = xh + tok * 16384 + pr * 256 + rot * 8;
                const u16t* lp = xl + tok * 16384 + pr * 256 + rot * 8;
                s16x8 bh = *(const s16x8*)bp;
                s16x8 bl = *(const s16x8*)lp;
                aT[tok][ct] = MFMA(th_, bh, aT[tok][ct]);
                aT[tok][ct] = MFMA(tl_, bh, aT[tok][ct]);
                aT[tok][ct] = MFMA(th_, bl, aT[tok][ct]);
                aP[tok][ct] = MFMA(ph_, bh, aP[tok][ct]);
                aP[tok][ct] = MFMA(pl_, bh, aP[tok][ct]);
                aP[tok][ct] = MFMA(ph_, bl, aP[tok][ct]);
                aG[tok][ct] = MFMA(gh_, bh, aG[tok][ct]);
                aG[tok][ct] = MFMA(gh_, bl, aG[tok][ct]);
            }
        }
    }

    // ---- epilogue
#pragma unroll
    for (int r = 0; r < 4; ++r) {
        int o = w * 16 + lg * 4 + r;
        float bvT = tb[o], bvP = pb[o], bvG = gbias[o];
#pragma unroll
        for (int tok = 0; tok < 2; ++tok) {
            size_t obase = ((size_t)b * 256 + n0 + tok) * 8192;
#pragma unroll
            for (int ct = 0; ct < 4; ++ct) {
                int s = ct * 16 + lr;
                size_t idx = obase + (size_t)o * 64 + s;
                out_t[idx] = aT[tok][ct][r] + bvT;
                out_p[idx] = aP[tok][ct][r] + bvP;
                out_g[idx] = f2bf(aG[tok][ct][r] + bvG);
            }
        }
    }
}

// ---------------- K3: QK^T, 3-term split, K-split 16 -------------------------
// XCD-chunk swizzle: logical blk = (phys&7)*64 + (phys>>3); the 4 (mt,nt)
// siblings of each (b,kc) are consecutive logical ids -> same XCD, L2-shared.
__global__ void __launch_bounds__(256) k_qk(
    const float* __restrict__ th_g, const float* __restrict__ ph_g, float* __restrict__ fp)
{
    __shared__ u16t th[128 * 40], tl[128 * 40], ph[128 * 40], pl[128 * 40];
    int phys = blockIdx.x;
    int blk = ((phys & 7) << 6) | (phys >> 3);
    int mt = blk & 1, nt = (blk >> 1) & 1, b = (blk >> 2) & 7, kc = blk >> 5;
    int n0 = nt * 128, m0 = mt * 128;
    int t = threadIdx.x;
    int w = t >> 6, l = t & 63, lr = l & 15, lg = l >> 4;
    int wn = (w & 1) * 64, wm = (w >> 1) * 64;
    f32x4 acc[4][4];
#pragma unroll
    for (int i = 0; i < 4; ++i)
#pragma unroll
        for (int j = 0; j < 4; ++j) acc[i][j] = (f32x4){0.f, 0.f, 0.f, 0.f};

    const float* tsrc = th_g + ((size_t)b * 256 + n0) * 8192 + kc * 512;
    const float* psrc = ph_g + ((size_t)b * 256 + m0) * 8192 + kc * 512;

    for (int kk = 0; kk < 16; ++kk) {
        __syncthreads();
#pragma unroll
        for (int i = 0; i < 8; ++i) {
            int row = i * 32 + (t >> 3);
            int q = t & 7;
            int r7 = row & 127;
            const float* sp = ((row < 128) ? (tsrc + (size_t)r7 * 8192)
                                           : (psrc + (size_t)r7 * 8192)) + kk * 32 + q * 4;
            float4 v = *(const float4*)sp;
            u16t* dh = ((row < 128) ? th : ph) + r7 * 40 + q * 4;
            u16t* dl = ((row < 128) ? tl : pl) + r7 * 40 + q * 4;
            u16t h0 = f2bf(v.x), h1 = f2bf(v.y), h2 = f2bf(v.z), h3 = f2bf(v.w);
            *(ushort2*)dh       = make_ushort2(h0, h1);
            *(ushort2*)(dh + 2) = make_ushort2(h2, h3);
            *(ushort2*)dl       = make_ushort2(f2bf(v.x - bf2f(h0)), f2bf(v.y - bf2f(h1)));
            *(ushort2*)(dl + 2) = make_ushort2(f2bf(v.z - bf2f(h2)), f2bf(v.w - bf2f(h3)));
        }
        __syncthreads();
        s16x8 a_h[4], a_l[4], b_h[4], b_l[4];
#pragma unroll
        for (int rt = 0; rt < 4; ++rt) {
            int row = wn + rt * 16 + lr;
            a_h[rt] = *(const s16x8*)(th + row * 40 + lg * 8);
            a_l[rt] = *(const s16x8*)(tl + row * 40 + lg * 8);
        }
#pragma unroll
        for (int ct = 0; ct < 4; ++ct) {
            int row = wm + ct * 16 + lr;
            b_h[ct] = *(const s16x8*)(ph + row * 40 + lg * 8);
            b_l[ct] = *(const s16x8*)(pl + row * 40 + lg * 8);
        }
#pragma unroll
        for (int rt = 0; rt < 4; ++rt)
#pragma unroll
            for (int ct = 0; ct < 4; ++ct) {
                acc[rt][ct] = MFMA(a_h[rt], b_h[ct], acc[rt][ct]);
                acc[rt][ct] = MFMA(a_l[rt], b_h[ct], acc[rt][ct]);
                acc[rt][ct] = MFMA(a_h[rt], b_l[ct], acc[rt][ct]);
            }
    }
    float* dst = fp + (size_t)kc * 524288 + ((size_t)b * 256 + n0 + wn) * 256 + m0 + wm;
#pragma unroll
    for (int rt = 0; rt < 4; ++rt)
#pragma unroll
        for (int r = 0; r < 4; ++r) {
            int nn = rt * 16 + lg * 4 + r;
#pragma unroll
            for (int ct = 0; ct < 4; ++ct)
                dst[(size_t)nn * 256 + ct * 16 + lr] = acc[rt][ct][r];
        }
}

// ---------------- K4: reduce partials + row softmax -> p bf16 ---------------
__global__ void __launch_bounds__(256) k_softmax(
    const float* __restrict__ fp, u16t* __restrict__ pout)
{
    int row = blockIdx.x * 4 + (threadIdx.x >> 6);
    int l = threadIdx.x & 63;
    const float* src = fp + (size_t)row * 256 + l * 4;
    float4 s = {0.f, 0.f, 0.f, 0.f};
#pragma unroll
    for (int kc = 0; kc < 16; ++kc) {
        float4 v = *(const float4*)(src + (size_t)kc * 524288);
        s.x += v.x; s.y += v.y; s.z += v.z; s.w += v.w;
    }
    float mx = fmaxf(fmaxf(s.x, s.y), fmaxf(s.z, s.w));
#pragma unroll
    for (int d = 1; d < 64; d <<= 1) mx = fmaxf(mx, __shfl_xor(mx, d));
    float e0 = expf(s.x - mx), e1 = expf(s.y - mx), e2 = expf(s.z - mx), e3 = expf(s.w - mx);
    float sm = e0 + e1 + e2 + e3;
#pragma unroll
    for (int d = 1; d < 64; d <<= 1) sm += __shfl_xor(sm, d);
    float r = 1.f / sm;
    u16t* dst = pout + (size_t)row * 256 + l * 4;
    *(ushort4*)dst = make_ushort4(f2bf(e0 * r), f2bf(e1 * r), f2bf(e2 * r), f2bf(e3 * r));
}

// ---------------- K5: y = p . g  (tile 64n x 256d, BK=64) --------------------
// nt-fastest decode + XCD-chunk swizzle: the 4 nt siblings of each (b,dt)
// are consecutive on one XCD -> g slice L2-shared. g staged transposed.
__global__ void __launch_bounds__(256) k_pv(
    const u16t* __restrict__ pin, const u16t* __restrict__ g, u16t* __restrict__ y)
{
    __shared__ u16t gl[256 * 72];
    int phys = blockIdx.x;
    int blk = ((phys & 7) << 7) | (phys >> 3);
    int nt = blk & 3, dt = (blk >> 2) & 31, b = blk >> 7;
    int n0 = nt * 64, d0 = dt * 256;
    int t = threadIdx.x, w = t >> 6, l = t & 63, lr = l & 15, lg = l >> 4;
    int wd = w * 64;
    f32x4 acc[4][4];
#pragma unroll
    for (int i = 0; i < 4; ++i)
#pragma unroll
        for (int j = 0; j < 4; ++j) acc[i][j] = (f32x4){0.f, 0.f, 0.f, 0.f};

    for (int kk = 0; kk < 4; ++kk) {
        __syncthreads();
        {   // stage g tile [64 m][256 d] -> gl[d][72] (transposed, scalar writes)
            int mloc = t >> 2, part = t & 3;
            const u16t* src = g + ((size_t)b * 256 + kk * 64 + mloc) * 8192 + d0 + part * 8;
#pragma unroll
            for (int i = 0; i < 8; ++i) {
                s16x8 v = *(const s16x8*)(src + i * 32);
                int dbase = part * 8 + i * 32;
#pragma unroll
                for (int j = 0; j < 8; ++j)
                    gl[(dbase + j) * 72 + mloc] = (u16t)v[j];
            }
        }
        __syncthreads();
#pragma unroll
        for (int kf = 0; kf < 2; ++kf) {
            s16x8 a[4];
#pragma unroll
            for (int rt = 0; rt < 4; ++rt)
                a[rt] = *(const s16x8*)(pin + ((size_t)b * 256 + n0 + rt * 16 + lr) * 256
                                        + kk * 64 + kf * 32 + lg * 8);
#pragma unroll
            for (int ct = 0; ct < 4; ++ct) {
                s16x8 bf = *(const s16x8*)(gl + (wd + ct * 16 + lr) * 72 + kf * 32 + lg * 8);
#pragma unroll
                for (int rt = 0; rt < 4; ++rt)
                    acc[rt][ct] = MFMA(a[rt], bf, acc[rt][ct]);
            }
        }
    }
    u16t* yb = y + ((size_t)b * 256 + n0) * 8192 + d0 + wd;
#pragma unroll
    for (int rt = 0; rt < 4; ++rt)
#pragma unroll
        for (int r = 0; r < 4; ++r) {
            int nn = rt * 16 + lg * 4 + r;
#pragma unroll
            for (int ct = 0; ct < 4; ++ct)
                yb[(size_t)nn * 8192 + ct * 16 + lr] = f2bf(acc[rt][ct][r]);
        }
}

// ---------------- K6: w_y = y . w_w + w_b, pixel-major bf16 + BN stats -------
__global__ void __launch_bounds__(128) k_wconv(
    const u16t* __restrict__ y, const u16t* __restrict__ wb, const float* __restrict__ w_b,
    u16t* __restrict__ wy, float* __restrict__ stats)
{
    __shared__ u16t yl[64 * 40];
    int blk = blockIdx.x;
    int b = blk >> 8, n = blk & 255;
    int t = threadIdx.x, w = t >> 6, l = t & 63, lr = l & 15, lg = l >> 4;
    int wo = w * 128;
    const u16t* wcv = wb + 163840;
    const u16t* yb = y + ((size_t)b * 256 + n) * 8192;
    f32x4 acc[4][8];
#pragma unroll
    for (int i = 0; i < 4; ++i)
#pragma unroll
        for (int j = 0; j < 8; ++j) acc[i][j] = (f32x4){0.f, 0.f, 0.f, 0.f};

    for (int kk = 0; kk < 4; ++kk) {
        __syncthreads();
        {   // stage 32c x 64s -> yl[s][40] (transposed, scalar writes)
            const u16t* src = yb + kk * 2048 + t * 16;
            int c = t >> 2, s0 = (t & 3) * 16;
            s16x8 v0 = *(const s16x8*)src;
            s16x8 v1 = *(const s16x8*)(src + 8);
#pragma unroll
            for (int j = 0; j < 8; ++j) {
                yl[(s0 + j) * 40 + c]     = (u16t)v0[j];
                yl[(s0 + 8 + j) * 40 + c] = (u16t)v1[j];
            }
        }
        __syncthreads();
        s16x8 a[4];
#pragma unroll
        for (int rt = 0; rt < 4; ++rt)
            a[rt] = *(const s16x8*)(yl + (rt * 16 + lr) * 40 + lg * 8);
#pragma unroll
        for (int ct = 0; ct < 8; ++ct) {
            int o = wo + ct * 16 + lr;
            s16x8 bf = *(const s16x8*)(wcv + o * 128 + kk * 32 + lg * 8);
#pragma unroll
            for (int rt = 0; rt < 4; ++rt)
                acc[rt][ct] = MFMA(a[rt], bf, acc[rt][ct]);
        }
    }
    u16t* wyb = wy + ((size_t)b * 16384 + n * 64) * 256;
    float s1[8], s2[8];
#pragma unroll
    for (int ct = 0; ct < 8; ++ct) { s1[ct] = 0.f; s2[ct] = 0.f; }
#pragma unroll
    for (int ct = 0; ct < 8; ++ct) {
        int o = wo + ct * 16 + lr;
        float bv = w_b[o];
#pragma unroll
        for (int rt = 0; rt < 4; ++rt)
#pragma unroll
            for (int r = 0; r < 4; ++r) {
                float v = acc[rt][ct][r] + bv;
                int s = rt * 16 + lg * 4 + r;
                wyb[(size_t)s * 256 + o] = f2bf(v);
                s1[ct] += v; s2[ct] += v * v;
            }
    }
#pragma unroll
    for (int ct = 0; ct < 8; ++ct) {
        s1[ct] += __shfl_xor(s1[ct], 16); s1[ct] += __shfl_xor(s1[ct], 32);
        s2[ct] += __shfl_xor(s2[ct], 16); s2[ct] += __shfl_xor(s2[ct], 32);
        if (lg == 0) {
            int o = wo + ct * 16 + lr;
            atomicAdd(&stats[o], s1[ct]);
            atomicAdd(&stats[256 + o], s2[ct]);
        }
    }
}

// ---------------- K7: BN + residual, fp32 out --------------------------------
__global__ void __launch_bounds__(256) k_final(
    const u16t* __restrict__ wy, const float* __restrict__ x, const float* __restrict__ stats,
    const float* __restrict__ gamma, const float* __restrict__ beta, float* __restrict__ out)
{
    __shared__ u16t lds[128 * 256];
    int blk = blockIdx.x;
    int b = blk >> 6, strip = blk & 63;
    int pi = strip >> 2, pjq = strip & 3;
    int t = threadIdx.x;
    int wh = t & 1, u = (t >> 1) & 7;
    int h0 = pi * 8;
    const float rcpN = 1.f / 131072.f;

    for (int ph2 = 0; ph2 < 2; ++ph2) {
        int n0 = pi * 16 + pjq * 4 + ph2 * 2;
        const u16t* src = wy + ((size_t)b * 16384 + n0 * 64) * 256;
        __syncthreads();
#pragma unroll
        for (int i = 0; i < 16; ++i) {
            int el = i * 2048 + t * 8;
            int pl = el >> 8;
            int oo = (t & 31) * 8;
            int os = (oo + (pl >> 3) * 8) & 255;
            *(s16x8*)(lds + pl * 256 + os) = *(const s16x8*)(src + el);
        }
        __syncthreads();
        int w0 = pjq * 32 + ph2 * 16;
        int shift2 = (wh * 8 + u) * 8;
#pragma unroll
        for (int i = 0; i < 16; ++i) {
            int oc = (t >> 4) + i * 16;
            float mm = stats[oc] * rcpN;
            float vv = stats[256 + oc] * rcpN - mm * mm;
            float aa = gamma[oc] * rsqrtf(vv + 1e-5f);
            float cc = beta[oc] - mm * aa;
            const u16t* lrow = lds + (wh * 64 + u * 8) * 256 + ((oc + shift2) & 255);
            size_t xidx = (((size_t)b * 256 + oc) * 128 + h0 + u) * 128 + w0 + wh * 8;
            float4 x0 = *(const float4*)(x + xidx);
            float4 x1 = *(const float4*)(x + xidx + 4);
            float4 o0, o1;
            o0.x = bf2f(lrow[0 * 256]) * aa + cc + x0.x;
            o0.y = bf2f(lrow[1 * 256]) * aa + cc + x0.y;
            o0.z = bf2f(lrow[2 * 256]) * aa + cc + x0.z;
            o0.w = bf2f(lrow[3 * 256]) * aa + cc + x0.w;
            o1.x = bf2f(lrow[4 * 256]) * aa + cc + x1.x;
            o1.y = bf2f(lrow[5 * 256]) * aa + cc + x1.y;
            o1.z = bf2f(lrow[6 * 256]) * aa + cc + x1.z;
            o1.w = bf2f(lrow[7 * 256]) * aa + cc + x1.w;
            *(float4*)(out + xidx) = o0;
            *(float4*)(out + xidx + 4) = o1;
        }
    }
}

// ---------------------------------------------------------------------------
extern "C" void kernel_launch(void* const* d_in, const int* in_sizes, int n_in,
                              void* d_out, int out_size, void* d_ws, size_t ws_size,
                              hipStream_t stream)
{
    (void)in_sizes; (void)n_in; (void)out_size;
    const float* x    = (const float*)d_in[0];
    const float* g_w  = (const float*)d_in[1];
    const float* g_b  = (const float*)d_in[2];
    const float* t_w  = (const float*)d_in[3];
    const float* t_b  = (const float*)d_in[4];
    const float* p_w  = (const float*)d_in[5];
    const float* p_b  = (const float*)d_in[6];
    const float* w_w  = (const float*)d_in[7];
    const float* w_b  = (const float*)d_in[8];
    const float* bn_g = (const float*)d_in[9];
    const float* bn_b = (const float*)d_in[10];

    const size_t G_OFF  = 0;
    const size_t FP_OFF = 33554432;
    const size_t WY_OFF = 33554432;          // aliases FP (dead after softmax)
    const size_t P_OFF  = 100663296;
    const size_t ST_OFF = 101711872;
    const size_t WB_OFF = 101713920;
    const size_t NEEDED = 102107136;
    if (ws_size < NEEDED) return;

    char* ws = (char*)d_ws;
    u16t*  g_buf = (u16t*)(ws + G_OFF);
    float* fp    = (float*)(ws + FP_OFF);
    u16t*  wy    = (u16t*)(ws + WY_OFF);
    u16t*  p_buf = (u16t*)(ws + P_OFF);
    float* stats = (float*)(ws + ST_OFF);
    u16t*  wb    = (u16t*)(ws + WB_OFF);

    float* th_g = (float*)d_out;             // theta fp32 (16.78M floats)
    float* ph_g = th_g + 16777216;           // phi fp32
    u16t*  y_buf = (u16t*)d_out;             // y bf16 (reuses d_out after QK)

    // allow 128KB dynamic LDS for k_proj (idempotent; ignore error)
    (void)hipFuncSetAttribute((const void*)k_proj,
                              hipFuncAttributeMaxDynamicSharedMemorySize, 131072);

    k_prep<<<128, 256, 0, stream>>>(g_w, t_w, p_w, w_w, wb, stats);
    k_proj<<<1024, 512, 131072, stream>>>(x, wb, t_b, p_b, g_b, th_g, ph_g, g_buf);
    k_qk<<<512, 256, 0, stream>>>(th_g, ph_g, fp);
    k_softmax<<<512, 256, 0, stream>>>(fp, p_buf);
    k_pv<<<1024, 256, 0, stream>>>(p_buf, g_buf, y_buf);
    k_wconv<<<2048, 128, 0, stream>>>(y_buf, wb, w_b, wy, stats);
    k_final<<<512, 256, 0, stream>>>(wy, x, stats, bn_g, bn_b, (float*)d_out);
}

// Round 11
// 372.725 us; speedup vs baseline: 1.0247x; 1.0247x over previous
//
#include <hip/hip_runtime.h>
#include <stdint.h>

// ---------------------------------------------------------------------------
// NonLocalBlockND: B=8, C_IN=256, C_INTER=128, H=W=128, P=16 -> tokens 256/batch,
// token dim D = 128*64 = 8192 (d = c*64 + s, s = u*8+v within 8x8 patch).
// Pipeline:
//   K1 prep   : weights -> bf16 (A-fragment swizzled, hi/lo split) + zero stats
//   K2 proj   : ONE token/block, 512 thr (8 waves), 64KB LDS -> 2 blocks/CU
//               (16 waves/CU): cross-block stage/compute overlap. Wave w owns
//               a 16-wide o-slice: per kk 5 weight frags feed 32 MFMAs.
//   K3 qk     : f = theta . phi (3-term bf16 split MFMA), K-split 16, XCD-chunked
//   K4 softmax: reduce partials, softmax rows -> p (bf16)
//   K5 pv     : y = p . g; nt-fastest + XCD-chunk; g staged transposed (b128)
//   K6 wconv  : w_y = y . w_w + w_b; y staged transposed -> b128 fragment reads
//   K7 final  : out = (w_y - mean)*rsqrt(var+eps)*gamma + beta + x   (fp32)
// ---------------------------------------------------------------------------

typedef unsigned short u16t;
typedef short s16x8 __attribute__((ext_vector_type(8)));
typedef float f32x4 __attribute__((ext_vector_type(4)));
typedef uint32_t u32x4 __attribute__((ext_vector_type(4)));

#define DEV __device__ __forceinline__

DEV u16t f2bf(float f) {
    union { float f; uint32_t u; } v; v.f = f;
    return (u16t)((v.u + 0x7FFFu + ((v.u >> 16) & 1u)) >> 16);
}
DEV float bf2f(u16t h) {
    union { uint32_t u; float f; } v; v.u = ((uint32_t)h) << 16; return v.f;
}
DEV f32x4 MFMA(s16x8 a, s16x8 b, f32x4 c) {
    return __builtin_amdgcn_mfma_f32_16x16x32_bf16(a, b, c, 0, 0, 0);
}

// ---------------- K1: weight prep -> bf16 + stats zero -----------------------
__global__ void __launch_bounds__(256) k_prep(
    const float* __restrict__ gw, const float* __restrict__ tw,
    const float* __restrict__ pw, const float* __restrict__ ww,
    u16t* __restrict__ wb, float* __restrict__ stats)
{
    int i = blockIdx.x * 256 + threadIdx.x;
    if (blockIdx.x == 0) {
        stats[threadIdx.x] = 0.f;
        stats[256 + threadIdx.x] = 0.f;
    }
    if (i >= 32768) return;
    int o = i >> 8, c = i & 255;
    int fi = ((o >> 4) * 8 + (c >> 5)) * 512 + (((c >> 3) & 3) * 16 + (o & 15)) * 8 + (c & 7);
    float t = tw[i], p = pw[i];
    u16t th = f2bf(t); u16t tl = f2bf(t - bf2f(th));
    u16t ph = f2bf(p); u16t pl = f2bf(p - bf2f(ph));
    wb[fi] = th; wb[32768 + fi] = tl;
    wb[65536 + fi] = ph; wb[98304 + fi] = pl;
    wb[131072 + fi] = f2bf(gw[i]);
    wb[163840 + i] = f2bf(ww[i]);
}

// ---------------- K2: projections, 1 token/block, 8 waves, 64KB LDS ---------
// 512 thr = 8 waves, 2 blocks/CU (16 waves/CU). x (64 pix x 256 c) staged
// hi/lo bf16 in 64KB LDS, [pix][256c], octet rot-swizzle oct'=(oct+pix)&31.
// Staging: wave w covers octets [4w,4w+4), lane = pixel.
// Compute: wave w owns o in [16w,16w+16) for all 3 projections;
// per kk: 5 disjoint weight frags -> 4 ct x {2 ds_read_b128 + 8 MFMA}.
__global__ void __launch_bounds__(512, 2) k_proj(
    const float* __restrict__ x, const u16t* __restrict__ wb,
    const float* __restrict__ tb, const float* __restrict__ pb, const float* __restrict__ gbias,
    float* __restrict__ out_t, float* __restrict__ out_p, u16t* __restrict__ out_g)
{
    __shared__ u16t xh[64 * 256];
    __shared__ u16t xl[64 * 256];
    int phys = blockIdx.x;
    int blk = ((phys & 7) << 8) | (phys >> 3);   // XCD chunking: one batch per XCD
    int b = blk >> 8, n = blk & 255;
    int pi = n >> 4, pj = n & 15;
    int t = threadIdx.x;
    int w = t >> 6, l = t & 63, lr = l & 15, lg = l >> 4;

    // ---- stage x hi/lo: lane = pixel, wave w covers octets [4w, 4w+4)
    {
        int p = l;
        const float* xb = x + (((size_t)b * 256) * 128 + pi * 8 + (p >> 3)) * 128 + pj * 8 + (p & 7);
#pragma unroll
        for (int i = 0; i < 4; ++i) {
            int octet = w * 4 + i;
            float v[8];
#pragma unroll
            for (int j = 0; j < 8; ++j) v[j] = xb[(size_t)(octet * 8 + j) * 16384];
            u32x4 hv, lv;
#pragma unroll
            for (int j = 0; j < 8; j += 2) {
                uint32_t u0 = __float_as_uint(v[j]), u1 = __float_as_uint(v[j + 1]);
                hv[j >> 1] = (u0 >> 16) | (u1 & 0xFFFF0000u);          // truncation hi
                float f0 = v[j]     - __uint_as_float(u0 & 0xFFFF0000u);
                float f1 = v[j + 1] - __uint_as_float(u1 & 0xFFFF0000u);
                lv[j >> 1] = (uint32_t)f2bf(f0) | ((uint32_t)f2bf(f1) << 16);  // RN lo
            }
            int oct2 = (octet + p) & 31;
            *(s16x8*)(xh + p * 256 + oct2 * 8) = __builtin_bit_cast(s16x8, hv);
            *(s16x8*)(xl + p * 256 + oct2 * 8) = __builtin_bit_cast(s16x8, lv);
        }
    }
    __syncthreads();

    f32x4 aT[4], aP[4], aG[4];
#pragma unroll
    for (int ct = 0; ct < 4; ++ct) {
        aT[ct] = (f32x4){0.f, 0.f, 0.f, 0.f};
        aP[ct] = (f32x4){0.f, 0.f, 0.f, 0.f};
        aG[ct] = (f32x4){0.f, 0.f, 0.f, 0.f};
    }

#pragma unroll
    for (int kk = 0; kk < 8; ++kk) {
        size_t off = (size_t)((w * 8 + kk) * 64 + l) * 8;
        s16x8 th_ = *(const s16x8*)(wb + off);
        s16x8 tl_ = *(const s16x8*)(wb + 32768 + off);
        s16x8 ph_ = *(const s16x8*)(wb + 65536 + off);
        s16x8 pl_ = *(const s16x8*)(wb + 98304 + off);
        s16x8 gh_ = *(const s16x8*)(wb + 131072 + off);
#pragma unroll
        for (int ct = 0; ct < 4; ++ct) {
            int pr = ct * 16 + lr;
            int rot = (kk * 4 + lg + pr) & 31;
            s16x8 bh = *(const s16x8*)(xh + pr * 256 + rot * 8);
            s16x8 bl = *(const s16x8*)(xl + pr * 256 + rot * 8);
            aT[ct] = MFMA(th_, bh, aT[ct]);
            aT[ct] = MFMA(tl_, bh, aT[ct]);
            aT[ct] = MFMA(th_, bl, aT[ct]);
            aP[ct] = MFMA(ph_, bh, aP[ct]);
            aP[ct] = MFMA(pl_, bh, aP[ct]);
            aP[ct] = MFMA(ph_, bl, aP[ct]);
            aG[ct] = MFMA(gh_, bh, aG[ct]);
            aG[ct] = MFMA(gh_, bl, aG[ct]);
        }
    }

    // ---- epilogue: D row=(lg*4+r) -> o within 16-tile ; col=ct*16+lr -> s
    size_t obase = ((size_t)b * 256 + n) * 8192;
#pragma unroll
    for (int r = 0; r < 4; ++r) {
        int o = w * 16 + lg * 4 + r;
        float bvT = tb[o], bvP = pb[o], bvG = gbias[o];
#pragma unroll
        for (int ct = 0; ct < 4; ++ct) {
            int s = ct * 16 + lr;
            size_t idx = obase + (size_t)o * 64 + s;
            out_t[idx] = aT[ct][r] + bvT;
            out_p[idx] = aP[ct][r] + bvP;
            out_g[idx] = f2bf(aG[ct][r] + bvG);
        }
    }
}

// ---------------- K3: QK^T, 3-term split, K-split 16 -------------------------
// XCD-chunk swizzle: the 4 (mt,nt) siblings of each (b,kc) land on one XCD.
__global__ void __launch_bounds__(256) k_qk(
    const float* __restrict__ th_g, const float* __restrict__ ph_g, float* __restrict__ fp)
{
    __shared__ u16t th[128 * 40], tl[128 * 40], ph[128 * 40], pl[128 * 40];
    int phys = blockIdx.x;
    int blk = ((phys & 7) << 6) | (phys >> 3);
    int mt = blk & 1, nt = (blk >> 1) & 1, b = (blk >> 2) & 7, kc = blk >> 5;
    int n0 = nt * 128, m0 = mt * 128;
    int t = threadIdx.x;
    int w = t >> 6, l = t & 63, lr = l & 15, lg = l >> 4;
    int wn = (w & 1) * 64, wm = (w >> 1) * 64;
    f32x4 acc[4][4];
#pragma unroll
    for (int i = 0; i < 4; ++i)
#pragma unroll
        for (int j = 0; j < 4; ++j) acc[i][j] = (f32x4){0.f, 0.f, 0.f, 0.f};

    const float* tsrc = th_g + ((size_t)b * 256 + n0) * 8192 + kc * 512;
    const float* psrc = ph_g + ((size_t)b * 256 + m0) * 8192 + kc * 512;

    for (int kk = 0; kk < 16; ++kk) {
        __syncthreads();
#pragma unroll
        for (int i = 0; i < 8; ++i) {
            int row = i * 32 + (t >> 3);
            int q = t & 7;
            int r7 = row & 127;
            const float* sp = ((row < 128) ? (tsrc + (size_t)r7 * 8192)
                                           : (psrc + (size_t)r7 * 8192)) + kk * 32 + q * 4;
            float4 v = *(const float4*)sp;
            u16t* dh = ((row < 128) ? th : ph) + r7 * 40 + q * 4;
            u16t* dl = ((row < 128) ? tl : pl) + r7 * 40 + q * 4;
            u16t h0 = f2bf(v.x), h1 = f2bf(v.y), h2 = f2bf(v.z), h3 = f2bf(v.w);
            *(ushort2*)dh       = make_ushort2(h0, h1);
            *(ushort2*)(dh + 2) = make_ushort2(h2, h3);
            *(ushort2*)dl       = make_ushort2(f2bf(v.x - bf2f(h0)), f2bf(v.y - bf2f(h1)));
            *(ushort2*)(dl + 2) = make_ushort2(f2bf(v.z - bf2f(h2)), f2bf(v.w - bf2f(h3)));
        }
        __syncthreads();
        s16x8 a_h[4], a_l[4], b_h[4], b_l[4];
#pragma unroll
        for (int rt = 0; rt < 4; ++rt) {
            int row = wn + rt * 16 + lr;
            a_h[rt] = *(const s16x8*)(th + row * 40 + lg * 8);
            a_l[rt] = *(const s16x8*)(tl + row * 40 + lg * 8);
        }
#pragma unroll
        for (int ct = 0; ct < 4; ++ct) {
            int row = wm + ct * 16 + lr;
            b_h[ct] = *(const s16x8*)(ph + row * 40 + lg * 8);
            b_l[ct] = *(const s16x8*)(pl + row * 40 + lg * 8);
        }
#pragma unroll
        for (int rt = 0; rt < 4; ++rt)
#pragma unroll
            for (int ct = 0; ct < 4; ++ct) {
                acc[rt][ct] = MFMA(a_h[rt], b_h[ct], acc[rt][ct]);
                acc[rt][ct] = MFMA(a_l[rt], b_h[ct], acc[rt][ct]);
                acc[rt][ct] = MFMA(a_h[rt], b_l[ct], acc[rt][ct]);
            }
    }
    float* dst = fp + (size_t)kc * 524288 + ((size_t)b * 256 + n0 + wn) * 256 + m0 + wm;
#pragma unroll
    for (int rt = 0; rt < 4; ++rt)
#pragma unroll
        for (int r = 0; r < 4; ++r) {
            int nn = rt * 16 + lg * 4 + r;
#pragma unroll
            for (int ct = 0; ct < 4; ++ct)
                dst[(size_t)nn * 256 + ct * 16 + lr] = acc[rt][ct][r];
        }
}

// ---------------- K4: reduce partials + row softmax -> p bf16 ---------------
__global__ void __launch_bounds__(256) k_softmax(
    const float* __restrict__ fp, u16t* __restrict__ pout)
{
    int row = blockIdx.x * 4 + (threadIdx.x >> 6);
    int l = threadIdx.x & 63;
    const float* src = fp + (size_t)row * 256 + l * 4;
    float4 s = {0.f, 0.f, 0.f, 0.f};
#pragma unroll
    for (int kc = 0; kc < 16; ++kc) {
        float4 v = *(const float4*)(src + (size_t)kc * 524288);
        s.x += v.x; s.y += v.y; s.z += v.z; s.w += v.w;
    }
    float mx = fmaxf(fmaxf(s.x, s.y), fmaxf(s.z, s.w));
#pragma unroll
    for (int d = 1; d < 64; d <<= 1) mx = fmaxf(mx, __shfl_xor(mx, d));
    float e0 = expf(s.x - mx), e1 = expf(s.y - mx), e2 = expf(s.z - mx), e3 = expf(s.w - mx);
    float sm = e0 + e1 + e2 + e3;
#pragma unroll
    for (int d = 1; d < 64; d <<= 1) sm += __shfl_xor(sm, d);
    float r = 1.f / sm;
    u16t* dst = pout + (size_t)row * 256 + l * 4;
    *(ushort4*)dst = make_ushort4(f2bf(e0 * r), f2bf(e1 * r), f2bf(e2 * r), f2bf(e3 * r));
}

// ---------------- K5: y = p . g  (tile 64n x 256d, BK=64) --------------------
__global__ void __launch_bounds__(256) k_pv(
    const u16t* __restrict__ pin, const u16t* __restrict__ g, u16t* __restrict__ y)
{
    __shared__ u16t gl[256 * 72];
    int phys = blockIdx.x;
    int blk = ((phys & 7) << 7) | (phys >> 3);
    int nt = blk & 3, dt = (blk >> 2) & 31, b = blk >> 7;
    int n0 = nt * 64, d0 = dt * 256;
    int t = threadIdx.x, w = t >> 6, l = t & 63, lr = l & 15, lg = l >> 4;
    int wd = w * 64;
    f32x4 acc[4][4];
#pragma unroll
    for (int i = 0; i < 4; ++i)
#pragma unroll
        for (int j = 0; j < 4; ++j) acc[i][j] = (f32x4){0.f, 0.f, 0.f, 0.f};

    for (int kk = 0; kk < 4; ++kk) {
        __syncthreads();
        {   // stage g tile [64 m][256 d] -> gl[d][72] (transposed, scalar writes)
            int mloc = t >> 2, part = t & 3;
            const u16t* src = g + ((size_t)b * 256 + kk * 64 + mloc) * 8192 + d0 + part * 8;
#pragma unroll
            for (int i = 0; i < 8; ++i) {
                s16x8 v = *(const s16x8*)(src + i * 32);
                int dbase = part * 8 + i * 32;
#pragma unroll
                for (int j = 0; j < 8; ++j)
                    gl[(dbase + j) * 72 + mloc] = (u16t)v[j];
            }
        }
        __syncthreads();
#pragma unroll
        for (int kf = 0; kf < 2; ++kf) {
            s16x8 a[4];
#pragma unroll
            for (int rt = 0; rt < 4; ++rt)
                a[rt] = *(const s16x8*)(pin + ((size_t)b * 256 + n0 + rt * 16 + lr) * 256
                                        + kk * 64 + kf * 32 + lg * 8);
#pragma unroll
            for (int ct = 0; ct < 4; ++ct) {
                s16x8 bf = *(const s16x8*)(gl + (wd + ct * 16 + lr) * 72 + kf * 32 + lg * 8);
#pragma unroll
                for (int rt = 0; rt < 4; ++rt)
                    acc[rt][ct] = MFMA(a[rt], bf, acc[rt][ct]);
            }
        }
    }
    u16t* yb = y + ((size_t)b * 256 + n0) * 8192 + d0 + wd;
#pragma unroll
    for (int rt = 0; rt < 4; ++rt)
#pragma unroll
        for (int r = 0; r < 4; ++r) {
            int nn = rt * 16 + lg * 4 + r;
#pragma unroll
            for (int ct = 0; ct < 4; ++ct)
                yb[(size_t)nn * 8192 + ct * 16 + lr] = f2bf(acc[rt][ct][r]);
        }
}

// ---------------- K6: w_y = y . w_w + w_b, pixel-major bf16 + BN stats -------
__global__ void __launch_bounds__(128) k_wconv(
    const u16t* __restrict__ y, const u16t* __restrict__ wb, const float* __restrict__ w_b,
    u16t* __restrict__ wy, float* __restrict__ stats)
{
    __shared__ u16t yl[64 * 40];
    int blk = blockIdx.x;
    int b = blk >> 8, n = blk & 255;
    int t = threadIdx.x, w = t >> 6, l = t & 63, lr = l & 15, lg = l >> 4;
    int wo = w * 128;
    const u16t* wcv = wb + 163840;
    const u16t* yb = y + ((size_t)b * 256 + n) * 8192;
    f32x4 acc[4][8];
#pragma unroll
    for (int i = 0; i < 4; ++i)
#pragma unroll
        for (int j = 0; j < 8; ++j) acc[i][j] = (f32x4){0.f, 0.f, 0.f, 0.f};

    for (int kk = 0; kk < 4; ++kk) {
        __syncthreads();
        {   // stage 32c x 64s -> yl[s][40] (transposed, scalar writes)
            const u16t* src = yb + kk * 2048 + t * 16;
            int c = t >> 2, s0 = (t & 3) * 16;
            s16x8 v0 = *(const s16x8*)src;
            s16x8 v1 = *(const s16x8*)(src + 8);
#pragma unroll
            for (int j = 0; j < 8; ++j) {
                yl[(s0 + j) * 40 + c]     = (u16t)v0[j];
                yl[(s0 + 8 + j) * 40 + c] = (u16t)v1[j];
            }
        }
        __syncthreads();
        s16x8 a[4];
#pragma unroll
        for (int rt = 0; rt < 4; ++rt)
            a[rt] = *(const s16x8*)(yl + (rt * 16 + lr) * 40 + lg * 8);
#pragma unroll
        for (int ct = 0; ct < 8; ++ct) {
            int o = wo + ct * 16 + lr;
            s16x8 bf = *(const s16x8*)(wcv + o * 128 + kk * 32 + lg * 8);
#pragma unroll
            for (int rt = 0; rt < 4; ++rt)
                acc[rt][ct] = MFMA(a[rt], bf, acc[rt][ct]);
        }
    }
    u16t* wyb = wy + ((size_t)b * 16384 + n * 64) * 256;
    float s1[8], s2[8];
#pragma unroll
    for (int ct = 0; ct < 8; ++ct) { s1[ct] = 0.f; s2[ct] = 0.f; }
#pragma unroll
    for (int ct = 0; ct < 8; ++ct) {
        int o = wo + ct * 16 + lr;
        float bv = w_b[o];
#pragma unroll
        for (int rt = 0; rt < 4; ++rt)
#pragma unroll
            for (int r = 0; r < 4; ++r) {
                float v = acc[rt][ct][r] + bv;
                int s = rt * 16 + lg * 4 + r;
                wyb[(size_t)s * 256 + o] = f2bf(v);
                s1[ct] += v; s2[ct] += v * v;
            }
    }
#pragma unroll
    for (int ct = 0; ct < 8; ++ct) {
        s1[ct] += __shfl_xor(s1[ct], 16); s1[ct] += __shfl_xor(s1[ct], 32);
        s2[ct] += __shfl_xor(s2[ct], 16); s2[ct] += __shfl_xor(s2[ct], 32);
        if (lg == 0) {
            int o = wo + ct * 16 + lr;
            atomicAdd(&stats[o], s1[ct]);
            atomicAdd(&stats[256 + o], s2[ct]);
        }
    }
}

// ---------------- K7: BN + residual, fp32 out --------------------------------
__global__ void __launch_bounds__(256) k_final(
    const u16t* __restrict__ wy, const float* __restrict__ x, const float* __restrict__ stats,
    const float* __restrict__ gamma, const float* __restrict__ beta, float* __restrict__ out)
{
    __shared__ u16t lds[128 * 256];
    int blk = blockIdx.x;
    int b = blk >> 6, strip = blk & 63;
    int pi = strip >> 2, pjq = strip & 3;
    int t = threadIdx.x;
    int wh = t & 1, u = (t >> 1) & 7;
    int h0 = pi * 8;
    const float rcpN = 1.f / 131072.f;

    for (int ph2 = 0; ph2 < 2; ++ph2) {
        int n0 = pi * 16 + pjq * 4 + ph2 * 2;
        const u16t* src = wy + ((size_t)b * 16384 + n0 * 64) * 256;
        __syncthreads();
#pragma unroll
        for (int i = 0; i < 16; ++i) {
            int el = i * 2048 + t * 8;
            int pl = el >> 8;
            int oo = (t & 31) * 8;
            int os = (oo + (pl >> 3) * 8) & 255;
            *(s16x8*)(lds + pl * 256 + os) = *(const s16x8*)(src + el);
        }
        __syncthreads();
        int w0 = pjq * 32 + ph2 * 16;
        int shift2 = (wh * 8 + u) * 8;
#pragma unroll
        for (int i = 0; i < 16; ++i) {
            int oc = (t >> 4) + i * 16;
            float mm = stats[oc] * rcpN;
            float vv = stats[256 + oc] * rcpN - mm * mm;
            float aa = gamma[oc] * rsqrtf(vv + 1e-5f);
            float cc = beta[oc] - mm * aa;
            const u16t* lrow = lds + (wh * 64 + u * 8) * 256 + ((oc + shift2) & 255);
            size_t xidx = (((size_t)b * 256 + oc) * 128 + h0 + u) * 128 + w0 + wh * 8;
            float4 x0 = *(const float4*)(x + xidx);
            float4 x1 = *(const float4*)(x + xidx + 4);
            float4 o0, o1;
            o0.x = bf2f(lrow[0 * 256]) * aa + cc + x0.x;
            o0.y = bf2f(lrow[1 * 256]) * aa + cc + x0.y;
            o0.z = bf2f(lrow[2 * 256]) * aa + cc + x0.z;
            o0.w = bf2f(lrow[3 * 256]) * aa + cc + x0.w;
            o1.x = bf2f(lrow[4 * 256]) * aa + cc + x1.x;
            o1.y = bf2f(lrow[5 * 256]) * aa + cc + x1.y;
            o1.z = bf2f(lrow[6 * 256]) * aa + cc + x1.z;
            o1.w = bf2f(lrow[7 * 256]) * aa + cc + x1.w;
            *(float4*)(out + xidx) = o0;
            *(float4*)(out + xidx + 4) = o1;
        }
    }
}

// ---------------------------------------------------------------------------
extern "C" void kernel_launch(void* const* d_in, const int* in_sizes, int n_in,
                              void* d_out, int out_size, void* d_ws, size_t ws_size,
                              hipStream_t stream)
{
    (void)in_sizes; (void)n_in; (void)out_size;
    const float* x    = (const float*)d_in[0];
    const float* g_w  = (const float*)d_in[1];
    const float* g_b  = (const float*)d_in[2];
    const float* t_w  = (const float*)d_in[3];
    const float* t_b  = (const float*)d_in[4];
    const float* p_w  = (const float*)d_in[5];
    const float* p_b  = (const float*)d_in[6];
    const float* w_w  = (const float*)d_in[7];
    const float* w_b  = (const float*)d_in[8];
    const float* bn_g = (const float*)d_in[9];
    const float* bn_b = (const float*)d_in[10];

    const size_t G_OFF  = 0;
    const size_t FP_OFF = 33554432;
    const size_t WY_OFF = 33554432;          // aliases FP (dead after softmax)
    const size_t P_OFF  = 100663296;
    const size_t ST_OFF = 101711872;
    const size_t WB_OFF = 101713920;
    const size_t NEEDED = 102107136;
    if (ws_size < NEEDED) return;

    char* ws = (char*)d_ws;
    u16t*  g_buf = (u16t*)(ws + G_OFF);
    float* fp    = (float*)(ws + FP_OFF);
    u16t*  wy    = (u16t*)(ws + WY_OFF);
    u16t*  p_buf = (u16t*)(ws + P_OFF);
    float* stats = (float*)(ws + ST_OFF);
    u16t*  wb    = (u16t*)(ws + WB_OFF);

    float* th_g = (float*)d_out;             // theta fp32 (16.78M floats)
    float* ph_g = th_g + 16777216;           // phi fp32
    u16t*  y_buf = (u16t*)d_out;             // y bf16 (reuses d_out after QK)

    k_prep<<<128, 256, 0, stream>>>(g_w, t_w, p_w, w_w, wb, stats);
    k_proj<<<2048, 512, 0, stream>>>(x, wb, t_b, p_b, g_b, th_g, ph_g, g_buf);
    k_qk<<<512, 256, 0, stream>>>(th_g, ph_g, fp);
    k_softmax<<<512, 256, 0, stream>>>(fp, p_buf);
    k_pv<<<1024, 256, 0, stream>>>(p_buf, g_buf, y_buf);
    k_wconv<<<2048, 128, 0, stream>>>(y_buf, wb, w_b, wy, stats);
    k_final<<<512, 256, 0, stream>>>(wy, x, stats, bn_g, bn_b, (float*)d_out);
}

// Round 12
// 348.248 us; speedup vs baseline: 1.0968x; 1.0703x over previous
//
#include <hip/hip_runtime.h>
#include <stdint.h>

// ---------------------------------------------------------------------------
// NonLocalBlockND: B=8, C_IN=256, C_INTER=128, H=W=128, P=16 -> tokens 256/batch,
// token dim D = 128*64 = 8192 (d = c*64 + s, s = u*8+v within 8x8 patch).
// Pipeline:
//   K1 prep   : weights -> bf16 (A-fragment swizzled, hi/lo split) + zero stats
//   K2 proj   : ONE token/block, 512 thr (8 waves), 64KB LDS -> 2 blocks/CU
//   K3 qk     : f = theta . phi (3-term bf16 split MFMA), K-split 16, XCD-chunked
//   K4 softmax: reduce partials, softmax rows -> p (bf16)
//   K5 pv     : y = p . g; nt-fastest + XCD-chunk; g staged transposed (b128)
//   K6 wconv  : w_y = y . w_w + w_b; wy written O-MAJOR per token
//               (wy[b][n][o][s]) so k_final needs no transpose. + BN stats.
//   K7 final  : pure streaming: thread=(oc,pj) reads 128B wy run, coalesced
//               x/out rows. No LDS, no barriers.
// ---------------------------------------------------------------------------

typedef unsigned short u16t;
typedef short s16x8 __attribute__((ext_vector_type(8)));
typedef float f32x4 __attribute__((ext_vector_type(4)));
typedef uint32_t u32x4 __attribute__((ext_vector_type(4)));

#define DEV __device__ __forceinline__

DEV u16t f2bf(float f) {
    union { float f; uint32_t u; } v; v.f = f;
    return (u16t)((v.u + 0x7FFFu + ((v.u >> 16) & 1u)) >> 16);
}
DEV float bf2f(u16t h) {
    union { uint32_t u; float f; } v; v.u = ((uint32_t)h) << 16; return v.f;
}
DEV f32x4 MFMA(s16x8 a, s16x8 b, f32x4 c) {
    return __builtin_amdgcn_mfma_f32_16x16x32_bf16(a, b, c, 0, 0, 0);
}

// ---------------- K1: weight prep -> bf16 + stats zero -----------------------
__global__ void __launch_bounds__(256) k_prep(
    const float* __restrict__ gw, const float* __restrict__ tw,
    const float* __restrict__ pw, const float* __restrict__ ww,
    u16t* __restrict__ wb, float* __restrict__ stats)
{
    int i = blockIdx.x * 256 + threadIdx.x;
    if (blockIdx.x == 0) {
        stats[threadIdx.x] = 0.f;
        stats[256 + threadIdx.x] = 0.f;
    }
    if (i >= 32768) return;
    int o = i >> 8, c = i & 255;
    int fi = ((o >> 4) * 8 + (c >> 5)) * 512 + (((c >> 3) & 3) * 16 + (o & 15)) * 8 + (c & 7);
    float t = tw[i], p = pw[i];
    u16t th = f2bf(t); u16t tl = f2bf(t - bf2f(th));
    u16t ph = f2bf(p); u16t pl = f2bf(p - bf2f(ph));
    wb[fi] = th; wb[32768 + fi] = tl;
    wb[65536 + fi] = ph; wb[98304 + fi] = pl;
    wb[131072 + fi] = f2bf(gw[i]);
    wb[163840 + i] = f2bf(ww[i]);
}

// ---------------- K2: projections, 1 token/block, 8 waves, 64KB LDS ---------
__global__ void __launch_bounds__(512, 2) k_proj(
    const float* __restrict__ x, const u16t* __restrict__ wb,
    const float* __restrict__ tb, const float* __restrict__ pb, const float* __restrict__ gbias,
    float* __restrict__ out_t, float* __restrict__ out_p, u16t* __restrict__ out_g)
{
    __shared__ u16t xh[64 * 256];
    __shared__ u16t xl[64 * 256];
    int phys = blockIdx.x;
    int blk = ((phys & 7) << 8) | (phys >> 3);   // XCD chunking: one batch per XCD
    int b = blk >> 8, n = blk & 255;
    int pi = n >> 4, pj = n & 15;
    int t = threadIdx.x;
    int w = t >> 6, l = t & 63, lr = l & 15, lg = l >> 4;

    // ---- stage x hi/lo: lane = pixel, wave w covers octets [4w, 4w+4)
    {
        int p = l;
        const float* xb = x + (((size_t)b * 256) * 128 + pi * 8 + (p >> 3)) * 128 + pj * 8 + (p & 7);
#pragma unroll
        for (int i = 0; i < 4; ++i) {
            int octet = w * 4 + i;
            float v[8];
#pragma unroll
            for (int j = 0; j < 8; ++j) v[j] = xb[(size_t)(octet * 8 + j) * 16384];
            u32x4 hv, lv;
#pragma unroll
            for (int j = 0; j < 8; j += 2) {
                uint32_t u0 = __float_as_uint(v[j]), u1 = __float_as_uint(v[j + 1]);
                hv[j >> 1] = (u0 >> 16) | (u1 & 0xFFFF0000u);          // truncation hi
                float f0 = v[j]     - __uint_as_float(u0 & 0xFFFF0000u);
                float f1 = v[j + 1] - __uint_as_float(u1 & 0xFFFF0000u);
                lv[j >> 1] = (uint32_t)f2bf(f0) | ((uint32_t)f2bf(f1) << 16);  // RN lo
            }
            int oct2 = (octet + p) & 31;
            *(s16x8*)(xh + p * 256 + oct2 * 8) = __builtin_bit_cast(s16x8, hv);
            *(s16x8*)(xl + p * 256 + oct2 * 8) = __builtin_bit_cast(s16x8, lv);
        }
    }
    __syncthreads();

    f32x4 aT[4], aP[4], aG[4];
#pragma unroll
    for (int ct = 0; ct < 4; ++ct) {
        aT[ct] = (f32x4){0.f, 0.f, 0.f, 0.f};
        aP[ct] = (f32x4){0.f, 0.f, 0.f, 0.f};
        aG[ct] = (f32x4){0.f, 0.f, 0.f, 0.f};
    }

#pragma unroll
    for (int kk = 0; kk < 8; ++kk) {
        size_t off = (size_t)((w * 8 + kk) * 64 + l) * 8;
        s16x8 th_ = *(const s16x8*)(wb + off);
        s16x8 tl_ = *(const s16x8*)(wb + 32768 + off);
        s16x8 ph_ = *(const s16x8*)(wb + 65536 + off);
        s16x8 pl_ = *(const s16x8*)(wb + 98304 + off);
        s16x8 gh_ = *(const s16x8*)(wb + 131072 + off);
#pragma unroll
        for (int ct = 0; ct < 4; ++ct) {
            int pr = ct * 16 + lr;
            int rot = (kk * 4 + lg + pr) & 31;
            s16x8 bh = *(const s16x8*)(xh + pr * 256 + rot * 8);
            s16x8 bl = *(const s16x8*)(xl + pr * 256 + rot * 8);
            aT[ct] = MFMA(th_, bh, aT[ct]);
            aT[ct] = MFMA(tl_, bh, aT[ct]);
            aT[ct] = MFMA(th_, bl, aT[ct]);
            aP[ct] = MFMA(ph_, bh, aP[ct]);
            aP[ct] = MFMA(pl_, bh, aP[ct]);
            aP[ct] = MFMA(ph_, bl, aP[ct]);
            aG[ct] = MFMA(gh_, bh, aG[ct]);
            aG[ct] = MFMA(gh_, bl, aG[ct]);
        }
    }

    // ---- epilogue
    size_t obase = ((size_t)b * 256 + n) * 8192;
#pragma unroll
    for (int r = 0; r < 4; ++r) {
        int o = w * 16 + lg * 4 + r;
        float bvT = tb[o], bvP = pb[o], bvG = gbias[o];
#pragma unroll
        for (int ct = 0; ct < 4; ++ct) {
            int s = ct * 16 + lr;
            size_t idx = obase + (size_t)o * 64 + s;
            out_t[idx] = aT[ct][r] + bvT;
            out_p[idx] = aP[ct][r] + bvP;
            out_g[idx] = f2bf(aG[ct][r] + bvG);
        }
    }
}

// ---------------- K3: QK^T, 3-term split, K-split 16 -------------------------
__global__ void __launch_bounds__(256) k_qk(
    const float* __restrict__ th_g, const float* __restrict__ ph_g, float* __restrict__ fp)
{
    __shared__ u16t th[128 * 40], tl[128 * 40], ph[128 * 40], pl[128 * 40];
    int phys = blockIdx.x;
    int blk = ((phys & 7) << 6) | (phys >> 3);
    int mt = blk & 1, nt = (blk >> 1) & 1, b = (blk >> 2) & 7, kc = blk >> 5;
    int n0 = nt * 128, m0 = mt * 128;
    int t = threadIdx.x;
    int w = t >> 6, l = t & 63, lr = l & 15, lg = l >> 4;
    int wn = (w & 1) * 64, wm = (w >> 1) * 64;
    f32x4 acc[4][4];
#pragma unroll
    for (int i = 0; i < 4; ++i)
#pragma unroll
        for (int j = 0; j < 4; ++j) acc[i][j] = (f32x4){0.f, 0.f, 0.f, 0.f};

    const float* tsrc = th_g + ((size_t)b * 256 + n0) * 8192 + kc * 512;
    const float* psrc = ph_g + ((size_t)b * 256 + m0) * 8192 + kc * 512;

    for (int kk = 0; kk < 16; ++kk) {
        __syncthreads();
#pragma unroll
        for (int i = 0; i < 8; ++i) {
            int row = i * 32 + (t >> 3);
            int q = t & 7;
            int r7 = row & 127;
            const float* sp = ((row < 128) ? (tsrc + (size_t)r7 * 8192)
                                           : (psrc + (size_t)r7 * 8192)) + kk * 32 + q * 4;
            float4 v = *(const float4*)sp;
            u16t* dh = ((row < 128) ? th : ph) + r7 * 40 + q * 4;
            u16t* dl = ((row < 128) ? tl : pl) + r7 * 40 + q * 4;
            u16t h0 = f2bf(v.x), h1 = f2bf(v.y), h2 = f2bf(v.z), h3 = f2bf(v.w);
            *(ushort2*)dh       = make_ushort2(h0, h1);
            *(ushort2*)(dh + 2) = make_ushort2(h2, h3);
            *(ushort2*)dl       = make_ushort2(f2bf(v.x - bf2f(h0)), f2bf(v.y - bf2f(h1)));
            *(ushort2*)(dl + 2) = make_ushort2(f2bf(v.z - bf2f(h2)), f2bf(v.w - bf2f(h3)));
        }
        __syncthreads();
        s16x8 a_h[4], a_l[4], b_h[4], b_l[4];
#pragma unroll
        for (int rt = 0; rt < 4; ++rt) {
            int row = wn + rt * 16 + lr;
            a_h[rt] = *(const s16x8*)(th + row * 40 + lg * 8);
            a_l[rt] = *(const s16x8*)(tl + row * 40 + lg * 8);
        }
#pragma unroll
        for (int ct = 0; ct < 4; ++ct) {
            int row = wm + ct * 16 + lr;
            b_h[ct] = *(const s16x8*)(ph + row * 40 + lg * 8);
            b_l[ct] = *(const s16x8*)(pl + row * 40 + lg * 8);
        }
#pragma unroll
        for (int rt = 0; rt < 4; ++rt)
#pragma unroll
            for (int ct = 0; ct < 4; ++ct) {
                acc[rt][ct] = MFMA(a_h[rt], b_h[ct], acc[rt][ct]);
                acc[rt][ct] = MFMA(a_l[rt], b_h[ct], acc[rt][ct]);
                acc[rt][ct] = MFMA(a_h[rt], b_l[ct], acc[rt][ct]);
            }
    }
    float* dst = fp + (size_t)kc * 524288 + ((size_t)b * 256 + n0 + wn) * 256 + m0 + wm;
#pragma unroll
    for (int rt = 0; rt < 4; ++rt)
#pragma unroll
        for (int r = 0; r < 4; ++r) {
            int nn = rt * 16 + lg * 4 + r;
#pragma unroll
            for (int ct = 0; ct < 4; ++ct)
                dst[(size_t)nn * 256 + ct * 16 + lr] = acc[rt][ct][r];
        }
}

// ---------------- K4: reduce partials + row softmax -> p bf16 ---------------
__global__ void __launch_bounds__(256) k_softmax(
    const float* __restrict__ fp, u16t* __restrict__ pout)
{
    int row = blockIdx.x * 4 + (threadIdx.x >> 6);
    int l = threadIdx.x & 63;
    const float* src = fp + (size_t)row * 256 + l * 4;
    float4 s = {0.f, 0.f, 0.f, 0.f};
#pragma unroll
    for (int kc = 0; kc < 16; ++kc) {
        float4 v = *(const float4*)(src + (size_t)kc * 524288);
        s.x += v.x; s.y += v.y; s.z += v.z; s.w += v.w;
    }
    float mx = fmaxf(fmaxf(s.x, s.y), fmaxf(s.z, s.w));
#pragma unroll
    for (int d = 1; d < 64; d <<= 1) mx = fmaxf(mx, __shfl_xor(mx, d));
    float e0 = expf(s.x - mx), e1 = expf(s.y - mx), e2 = expf(s.z - mx), e3 = expf(s.w - mx);
    float sm = e0 + e1 + e2 + e3;
#pragma unroll
    for (int d = 1; d < 64; d <<= 1) sm += __shfl_xor(sm, d);
    float r = 1.f / sm;
    u16t* dst = pout + (size_t)row * 256 + l * 4;
    *(ushort4*)dst = make_ushort4(f2bf(e0 * r), f2bf(e1 * r), f2bf(e2 * r), f2bf(e3 * r));
}

// ---------------- K5: y = p . g  (tile 64n x 256d, BK=64) --------------------
__global__ void __launch_bounds__(256) k_pv(
    const u16t* __restrict__ pin, const u16t* __restrict__ g, u16t* __restrict__ y)
{
    __shared__ u16t gl[256 * 72];
    int phys = blockIdx.x;
    int blk = ((phys & 7) << 7) | (phys >> 3);
    int nt = blk & 3, dt = (blk >> 2) & 31, b = blk >> 7;
    int n0 = nt * 64, d0 = dt * 256;
    int t = threadIdx.x, w = t >> 6, l = t & 63, lr = l & 15, lg = l >> 4;
    int wd = w * 64;
    f32x4 acc[4][4];
#pragma unroll
    for (int i = 0; i < 4; ++i)
#pragma unroll
        for (int j = 0; j < 4; ++j) acc[i][j] = (f32x4){0.f, 0.f, 0.f, 0.f};

    for (int kk = 0; kk < 4; ++kk) {
        __syncthreads();
        {   // stage g tile [64 m][256 d] -> gl[d][72] (transposed, scalar writes)
            int mloc = t >> 2, part = t & 3;
            const u16t* src = g + ((size_t)b * 256 + kk * 64 + mloc) * 8192 + d0 + part * 8;
#pragma unroll
            for (int i = 0; i < 8; ++i) {
                s16x8 v = *(const s16x8*)(src + i * 32);
                int dbase = part * 8 + i * 32;
#pragma unroll
                for (int j = 0; j < 8; ++j)
                    gl[(dbase + j) * 72 + mloc] = (u16t)v[j];
            }
        }
        __syncthreads();
#pragma unroll
        for (int kf = 0; kf < 2; ++kf) {
            s16x8 a[4];
#pragma unroll
            for (int rt = 0; rt < 4; ++rt)
                a[rt] = *(const s16x8*)(pin + ((size_t)b * 256 + n0 + rt * 16 + lr) * 256
                                        + kk * 64 + kf * 32 + lg * 8);
#pragma unroll
            for (int ct = 0; ct < 4; ++ct) {
                s16x8 bf = *(const s16x8*)(gl + (wd + ct * 16 + lr) * 72 + kf * 32 + lg * 8);
#pragma unroll
                for (int rt = 0; rt < 4; ++rt)
                    acc[rt][ct] = MFMA(a[rt], bf, acc[rt][ct]);
            }
        }
    }
    u16t* yb = y + ((size_t)b * 256 + n0) * 8192 + d0 + wd;
#pragma unroll
    for (int rt = 0; rt < 4; ++rt)
#pragma unroll
        for (int r = 0; r < 4; ++r) {
            int nn = rt * 16 + lg * 4 + r;
#pragma unroll
            for (int ct = 0; ct < 4; ++ct)
                yb[(size_t)nn * 8192 + ct * 16 + lr] = f2bf(acc[rt][ct][r]);
        }
}

// ---------------- K6: w_y = y . w_w + w_b -> wy[b][n][o][s] + BN stats -------
__global__ void __launch_bounds__(128) k_wconv(
    const u16t* __restrict__ y, const u16t* __restrict__ wb, const float* __restrict__ w_b,
    u16t* __restrict__ wy, float* __restrict__ stats)
{
    __shared__ u16t yl[64 * 40];
    int blk = blockIdx.x;
    int b = blk >> 8, n = blk & 255;
    int t = threadIdx.x, w = t >> 6, l = t & 63, lr = l & 15, lg = l >> 4;
    int wo = w * 128;
    const u16t* wcv = wb + 163840;
    const u16t* yb = y + ((size_t)b * 256 + n) * 8192;
    f32x4 acc[4][8];
#pragma unroll
    for (int i = 0; i < 4; ++i)
#pragma unroll
        for (int j = 0; j < 8; ++j) acc[i][j] = (f32x4){0.f, 0.f, 0.f, 0.f};

    for (int kk = 0; kk < 4; ++kk) {
        __syncthreads();
        {   // stage 32c x 64s -> yl[s][40] (transposed, scalar writes)
            const u16t* src = yb + kk * 2048 + t * 16;
            int c = t >> 2, s0 = (t & 3) * 16;
            s16x8 v0 = *(const s16x8*)src;
            s16x8 v1 = *(const s16x8*)(src + 8);
#pragma unroll
            for (int j = 0; j < 8; ++j) {
                yl[(s0 + j) * 40 + c]     = (u16t)v0[j];
                yl[(s0 + 8 + j) * 40 + c] = (u16t)v1[j];
            }
        }
        __syncthreads();
        s16x8 a[4];
#pragma unroll
        for (int rt = 0; rt < 4; ++rt)
            a[rt] = *(const s16x8*)(yl + (rt * 16 + lr) * 40 + lg * 8);
#pragma unroll
        for (int ct = 0; ct < 8; ++ct) {
            int o = wo + ct * 16 + lr;
            s16x8 bf = *(const s16x8*)(wcv + o * 128 + kk * 32 + lg * 8);
#pragma unroll
            for (int rt = 0; rt < 4; ++rt)
                acc[rt][ct] = MFMA(a[rt], bf, acc[rt][ct]);
        }
    }
    // ---- epilogue: wy[b][n][o][s] (o-major token tile), ushort4 stores ------
    u16t* wyb = wy + ((size_t)b * 256 + n) * 16384;
    float s1[8], s2[8];
#pragma unroll
    for (int ct = 0; ct < 8; ++ct) { s1[ct] = 0.f; s2[ct] = 0.f; }
#pragma unroll
    for (int ct = 0; ct < 8; ++ct) {
        int o = wo + ct * 16 + lr;
        float bv = w_b[o];
#pragma unroll
        for (int rt = 0; rt < 4; ++rt) {
            float v0 = acc[rt][ct][0] + bv;
            float v1 = acc[rt][ct][1] + bv;
            float v2 = acc[rt][ct][2] + bv;
            float v3 = acc[rt][ct][3] + bv;
            s1[ct] += v0 + v1 + v2 + v3;
            s2[ct] += v0 * v0 + v1 * v1 + v2 * v2 + v3 * v3;
            *(ushort4*)(wyb + o * 64 + rt * 16 + lg * 4) =
                make_ushort4(f2bf(v0), f2bf(v1), f2bf(v2), f2bf(v3));
        }
    }
#pragma unroll
    for (int ct = 0; ct < 8; ++ct) {
        s1[ct] += __shfl_xor(s1[ct], 16); s1[ct] += __shfl_xor(s1[ct], 32);
        s2[ct] += __shfl_xor(s2[ct], 16); s2[ct] += __shfl_xor(s2[ct], 32);
        if (lg == 0) {
            int o = wo + ct * 16 + lr;
            atomicAdd(&stats[o], s1[ct]);
            atomicAdd(&stats[256 + o], s2[ct]);
        }
    }
}

// ---------------- K7: BN + residual, pure streaming (no LDS) -----------------
// grid 2048 = b(8) x pi(16) x ocg(16); 256 thr = ocs(16) x pj(16).
// Thread: (b, pi, oc=ocg*16+ocs, pj): reads wy[b][n][oc][0..64) (128B run),
// then per u: coalesced float4 x-reads / out-writes (lanes pj cover 512B row).
__global__ void __launch_bounds__(256) k_final(
    const u16t* __restrict__ wy, const float* __restrict__ x, const float* __restrict__ stats,
    const float* __restrict__ gamma, const float* __restrict__ beta, float* __restrict__ out)
{
    int blk = blockIdx.x;
    int ocg = blk & 15, pi = (blk >> 4) & 15, b = blk >> 8;
    int t = threadIdx.x;
    int pj = t & 15, ocs = t >> 4;
    int oc = ocg * 16 + ocs;
    int n = pi * 16 + pj;
    const float rcpN = 1.f / 131072.f;
    float mm = stats[oc] * rcpN;
    float vv = stats[256 + oc] * rcpN - mm * mm;
    float aa = gamma[oc] * rsqrtf(vv + 1e-5f);
    float cc = beta[oc] - mm * aa;
    const u16t* wyt = wy + (((size_t)b * 256 + n) * 256 + oc) * 64;
    size_t xbase = (((size_t)b * 256 + oc) * 128 + (size_t)pi * 8) * 128 + pj * 8;
#pragma unroll
    for (int u = 0; u < 8; ++u) {
        s16x8 v = *(const s16x8*)(wyt + u * 8);
        size_t xi = xbase + (size_t)u * 128;
        float4 x0 = *(const float4*)(x + xi);
        float4 x1 = *(const float4*)(x + xi + 4);
        float4 o0, o1;
        o0.x = bf2f((u16t)v[0]) * aa + cc + x0.x;
        o0.y = bf2f((u16t)v[1]) * aa + cc + x0.y;
        o0.z = bf2f((u16t)v[2]) * aa + cc + x0.z;
        o0.w = bf2f((u16t)v[3]) * aa + cc + x0.w;
        o1.x = bf2f((u16t)v[4]) * aa + cc + x1.x;
        o1.y = bf2f((u16t)v[5]) * aa + cc + x1.y;
        o1.z = bf2f((u16t)v[6]) * aa + cc + x1.z;
        o1.w = bf2f((u16t)v[7]) * aa + cc + x1.w;
        *(float4*)(out + xi) = o0;
        *(float4*)(out + xi + 4) = o1;
    }
}

// ---------------------------------------------------------------------------
extern "C" void kernel_launch(void* const* d_in, const int* in_sizes, int n_in,
                              void* d_out, int out_size, void* d_ws, size_t ws_size,
                              hipStream_t stream)
{
    (void)in_sizes; (void)n_in; (void)out_size;
    const float* x    = (const float*)d_in[0];
    const float* g_w  = (const float*)d_in[1];
    const float* g_b  = (const float*)d_in[2];
    const float* t_w  = (const float*)d_in[3];
    const float* t_b  = (const float*)d_in[4];
    const float* p_w  = (const float*)d_in[5];
    const float* p_b  = (const float*)d_in[6];
    const float* w_w  = (const float*)d_in[7];
    const float* w_b  = (const float*)d_in[8];
    const float* bn_g = (const float*)d_in[9];
    const float* bn_b = (const float*)d_in[10];

    const size_t G_OFF  = 0;
    const size_t FP_OFF = 33554432;
    const size_t WY_OFF = 33554432;          // aliases FP (dead after softmax)
    const size_t P_OFF  = 100663296;
    const size_t ST_OFF = 101711872;
    const size_t WB_OFF = 101713920;
    const size_t NEEDED = 102107136;
    if (ws_size < NEEDED) return;

    char* ws = (char*)d_ws;
    u16t*  g_buf = (u16t*)(ws + G_OFF);
    float* fp    = (float*)(ws + FP_OFF);
    u16t*  wy    = (u16t*)(ws + WY_OFF);
    u16t*  p_buf = (u16t*)(ws + P_OFF);
    float* stats = (float*)(ws + ST_OFF);
    u16t*  wb    = (u16t*)(ws + WB_OFF);

    float* th_g = (float*)d_out;             // theta fp32 (16.78M floats)
    float* ph_g = th_g + 16777216;           // phi fp32
    u16t*  y_buf = (u16t*)d_out;             // y bf16 (reuses d_out after QK)

    k_prep<<<128, 256, 0, stream>>>(g_w, t_w, p_w, w_w, wb, stats);
    k_proj<<<2048, 512, 0, stream>>>(x, wb, t_b, p_b, g_b, th_g, ph_g, g_buf);
    k_qk<<<512, 256, 0, stream>>>(th_g, ph_g, fp);
    k_softmax<<<512, 256, 0, stream>>>(fp, p_buf);
    k_pv<<<1024, 256, 0, stream>>>(p_buf, g_buf, y_buf);
    k_wconv<<<2048, 128, 0, stream>>>(y_buf, wb, w_b, wy, stats);
    k_final<<<2048, 256, 0, stream>>>(wy, x, stats, bn_g, bn_b, (float*)d_out);
}

// Round 13
// 340.008 us; speedup vs baseline: 1.1233x; 1.0242x over previous
//
#include <hip/hip_runtime.h>
#include <stdint.h>

// ---------------------------------------------------------------------------
// NonLocalBlockND: B=8, C_IN=256, C_INTER=128, H=W=128, P=16 -> tokens 256/batch,
// token dim D = 128*64 = 8192 (d = c*64 + s, s = u*8+v within 8x8 patch).
// Pipeline:
//   K1 prep   : weights -> bf16 (A-fragment swizzled, hi/lo split) + zero stats
//   K2 proj   : ONE token/block, 512 thr (8 waves), 64KB LDS -> 2 blocks/CU
//   K3 qk     : f = theta . phi (3-term bf16 split MFMA), K-split 16, XCD-chunked
//   K4 softmax: reduce partials, softmax rows -> p (bf16)
//   K5 pv     : y = p . g; ONE block per (b, 64-d slice): g staged ONCE
//               (transposed gl[d][m], stride 266), all 256 n per block ->
//               g read exactly once (saves ~100MB HBM vs nt-split).
//   K6 wconv  : w_y = y . w_w + w_b; wy written O-MAJOR per token + BN stats
//   K7 final  : pure streaming BN+residual (no LDS, no barriers)
// ---------------------------------------------------------------------------

typedef unsigned short u16t;
typedef short s16x8 __attribute__((ext_vector_type(8)));
typedef float f32x4 __attribute__((ext_vector_type(4)));
typedef uint32_t u32x4 __attribute__((ext_vector_type(4)));

#define DEV __device__ __forceinline__

DEV u16t f2bf(float f) {
    union { float f; uint32_t u; } v; v.f = f;
    return (u16t)((v.u + 0x7FFFu + ((v.u >> 16) & 1u)) >> 16);
}
DEV float bf2f(u16t h) {
    union { uint32_t u; float f; } v; v.u = ((uint32_t)h) << 16; return v.f;
}
DEV f32x4 MFMA(s16x8 a, s16x8 b, f32x4 c) {
    return __builtin_amdgcn_mfma_f32_16x16x32_bf16(a, b, c, 0, 0, 0);
}

// ---------------- K1: weight prep -> bf16 + stats zero -----------------------
__global__ void __launch_bounds__(256) k_prep(
    const float* __restrict__ gw, const float* __restrict__ tw,
    const float* __restrict__ pw, const float* __restrict__ ww,
    u16t* __restrict__ wb, float* __restrict__ stats)
{
    int i = blockIdx.x * 256 + threadIdx.x;
    if (blockIdx.x == 0) {
        stats[threadIdx.x] = 0.f;
        stats[256 + threadIdx.x] = 0.f;
    }
    if (i >= 32768) return;
    int o = i >> 8, c = i & 255;
    int fi = ((o >> 4) * 8 + (c >> 5)) * 512 + (((c >> 3) & 3) * 16 + (o & 15)) * 8 + (c & 7);
    float t = tw[i], p = pw[i];
    u16t th = f2bf(t); u16t tl = f2bf(t - bf2f(th));
    u16t ph = f2bf(p); u16t pl = f2bf(p - bf2f(ph));
    wb[fi] = th; wb[32768 + fi] = tl;
    wb[65536 + fi] = ph; wb[98304 + fi] = pl;
    wb[131072 + fi] = f2bf(gw[i]);
    wb[163840 + i] = f2bf(ww[i]);
}

// ---------------- K2: projections, 1 token/block, 8 waves, 64KB LDS ---------
__global__ void __launch_bounds__(512, 2) k_proj(
    const float* __restrict__ x, const u16t* __restrict__ wb,
    const float* __restrict__ tb, const float* __restrict__ pb, const float* __restrict__ gbias,
    float* __restrict__ out_t, float* __restrict__ out_p, u16t* __restrict__ out_g)
{
    __shared__ u16t xh[64 * 256];
    __shared__ u16t xl[64 * 256];
    int phys = blockIdx.x;
    int blk = ((phys & 7) << 8) | (phys >> 3);   // XCD chunking: one batch per XCD
    int b = blk >> 8, n = blk & 255;
    int pi = n >> 4, pj = n & 15;
    int t = threadIdx.x;
    int w = t >> 6, l = t & 63, lr = l & 15, lg = l >> 4;

    // ---- stage x hi/lo: lane = pixel, wave w covers octets [4w, 4w+4)
    {
        int p = l;
        const float* xb = x + (((size_t)b * 256) * 128 + pi * 8 + (p >> 3)) * 128 + pj * 8 + (p & 7);
#pragma unroll
        for (int i = 0; i < 4; ++i) {
            int octet = w * 4 + i;
            float v[8];
#pragma unroll
            for (int j = 0; j < 8; ++j) v[j] = xb[(size_t)(octet * 8 + j) * 16384];
            u32x4 hv, lv;
#pragma unroll
            for (int j = 0; j < 8; j += 2) {
                uint32_t u0 = __float_as_uint(v[j]), u1 = __float_as_uint(v[j + 1]);
                hv[j >> 1] = (u0 >> 16) | (u1 & 0xFFFF0000u);          // truncation hi
                float f0 = v[j]     - __uint_as_float(u0 & 0xFFFF0000u);
                float f1 = v[j + 1] - __uint_as_float(u1 & 0xFFFF0000u);
                lv[j >> 1] = (uint32_t)f2bf(f0) | ((uint32_t)f2bf(f1) << 16);  // RN lo
            }
            int oct2 = (octet + p) & 31;
            *(s16x8*)(xh + p * 256 + oct2 * 8) = __builtin_bit_cast(s16x8, hv);
            *(s16x8*)(xl + p * 256 + oct2 * 8) = __builtin_bit_cast(s16x8, lv);
        }
    }
    __syncthreads();

    f32x4 aT[4], aP[4], aG[4];
#pragma unroll
    for (int ct = 0; ct < 4; ++ct) {
        aT[ct] = (f32x4){0.f, 0.f, 0.f, 0.f};
        aP[ct] = (f32x4){0.f, 0.f, 0.f, 0.f};
        aG[ct] = (f32x4){0.f, 0.f, 0.f, 0.f};
    }

#pragma unroll
    for (int kk = 0; kk < 8; ++kk) {
        size_t off = (size_t)((w * 8 + kk) * 64 + l) * 8;
        s16x8 th_ = *(const s16x8*)(wb + off);
        s16x8 tl_ = *(const s16x8*)(wb + 32768 + off);
        s16x8 ph_ = *(const s16x8*)(wb + 65536 + off);
        s16x8 pl_ = *(const s16x8*)(wb + 98304 + off);
        s16x8 gh_ = *(const s16x8*)(wb + 131072 + off);
#pragma unroll
        for (int ct = 0; ct < 4; ++ct) {
            int pr = ct * 16 + lr;
            int rot = (kk * 4 + lg + pr) & 31;
            s16x8 bh = *(const s16x8*)(xh + pr * 256 + rot * 8);
            s16x8 bl = *(const s16x8*)(xl + pr * 256 + rot * 8);
            aT[ct] = MFMA(th_, bh, aT[ct]);
            aT[ct] = MFMA(tl_, bh, aT[ct]);
            aT[ct] = MFMA(th_, bl, aT[ct]);
            aP[ct] = MFMA(ph_, bh, aP[ct]);
            aP[ct] = MFMA(pl_, bh, aP[ct]);
            aP[ct] = MFMA(ph_, bl, aP[ct]);
            aG[ct] = MFMA(gh_, bh, aG[ct]);
            aG[ct] = MFMA(gh_, bl, aG[ct]);
        }
    }

    // ---- epilogue
    size_t obase = ((size_t)b * 256 + n) * 8192;
#pragma unroll
    for (int r = 0; r < 4; ++r) {
        int o = w * 16 + lg * 4 + r;
        float bvT = tb[o], bvP = pb[o], bvG = gbias[o];
#pragma unroll
        for (int ct = 0; ct < 4; ++ct) {
            int s = ct * 16 + lr;
            size_t idx = obase + (size_t)o * 64 + s;
            out_t[idx] = aT[ct][r] + bvT;
            out_p[idx] = aP[ct][r] + bvP;
            out_g[idx] = f2bf(aG[ct][r] + bvG);
        }
    }
}

// ---------------- K3: QK^T, 3-term split, K-split 16 -------------------------
__global__ void __launch_bounds__(256) k_qk(
    const float* __restrict__ th_g, const float* __restrict__ ph_g, float* __restrict__ fp)
{
    __shared__ u16t th[128 * 40], tl[128 * 40], ph[128 * 40], pl[128 * 40];
    int phys = blockIdx.x;
    int blk = ((phys & 7) << 6) | (phys >> 3);
    int mt = blk & 1, nt = (blk >> 1) & 1, b = (blk >> 2) & 7, kc = blk >> 5;
    int n0 = nt * 128, m0 = mt * 128;
    int t = threadIdx.x;
    int w = t >> 6, l = t & 63, lr = l & 15, lg = l >> 4;
    int wn = (w & 1) * 64, wm = (w >> 1) * 64;
    f32x4 acc[4][4];
#pragma unroll
    for (int i = 0; i < 4; ++i)
#pragma unroll
        for (int j = 0; j < 4; ++j) acc[i][j] = (f32x4){0.f, 0.f, 0.f, 0.f};

    const float* tsrc = th_g + ((size_t)b * 256 + n0) * 8192 + kc * 512;
    const float* psrc = ph_g + ((size_t)b * 256 + m0) * 8192 + kc * 512;

    for (int kk = 0; kk < 16; ++kk) {
        __syncthreads();
#pragma unroll
        for (int i = 0; i < 8; ++i) {
            int row = i * 32 + (t >> 3);
            int q = t & 7;
            int r7 = row & 127;
            const float* sp = ((row < 128) ? (tsrc + (size_t)r7 * 8192)
                                           : (psrc + (size_t)r7 * 8192)) + kk * 32 + q * 4;
            float4 v = *(const float4*)sp;
            u16t* dh = ((row < 128) ? th : ph) + r7 * 40 + q * 4;
            u16t* dl = ((row < 128) ? tl : pl) + r7 * 40 + q * 4;
            u16t h0 = f2bf(v.x), h1 = f2bf(v.y), h2 = f2bf(v.z), h3 = f2bf(v.w);
            *(ushort2*)dh       = make_ushort2(h0, h1);
            *(ushort2*)(dh + 2) = make_ushort2(h2, h3);
            *(ushort2*)dl       = make_ushort2(f2bf(v.x - bf2f(h0)), f2bf(v.y - bf2f(h1)));
            *(ushort2*)(dl + 2) = make_ushort2(f2bf(v.z - bf2f(h2)), f2bf(v.w - bf2f(h3)));
        }
        __syncthreads();
        s16x8 a_h[4], a_l[4], b_h[4], b_l[4];
#pragma unroll
        for (int rt = 0; rt < 4; ++rt) {
            int row = wn + rt * 16 + lr;
            a_h[rt] = *(const s16x8*)(th + row * 40 + lg * 8);
            a_l[rt] = *(const s16x8*)(tl + row * 40 + lg * 8);
        }
#pragma unroll
        for (int ct = 0; ct < 4; ++ct) {
            int row = wm + ct * 16 + lr;
            b_h[ct] = *(const s16x8*)(ph + row * 40 + lg * 8);
            b_l[ct] = *(const s16x8*)(pl + row * 40 + lg * 8);
        }
#pragma unroll
        for (int rt = 0; rt < 4; ++rt)
#pragma unroll
            for (int ct = 0; ct < 4; ++ct) {
                acc[rt][ct] = MFMA(a_h[rt], b_h[ct], acc[rt][ct]);
                acc[rt][ct] = MFMA(a_l[rt], b_h[ct], acc[rt][ct]);
                acc[rt][ct] = MFMA(a_h[rt], b_l[ct], acc[rt][ct]);
            }
    }
    float* dst = fp + (size_t)kc * 524288 + ((size_t)b * 256 + n0 + wn) * 256 + m0 + wm;
#pragma unroll
    for (int rt = 0; rt < 4; ++rt)
#pragma unroll
        for (int r = 0; r < 4; ++r) {
            int nn = rt * 16 + lg * 4 + r;
#pragma unroll
            for (int ct = 0; ct < 4; ++ct)
                dst[(size_t)nn * 256 + ct * 16 + lr] = acc[rt][ct][r];
        }
}

// ---------------- K4: reduce partials + row softmax -> p bf16 ---------------
__global__ void __launch_bounds__(256) k_softmax(
    const float* __restrict__ fp, u16t* __restrict__ pout)
{
    int row = blockIdx.x * 4 + (threadIdx.x >> 6);
    int l = threadIdx.x & 63;
    const float* src = fp + (size_t)row * 256 + l * 4;
    float4 s = {0.f, 0.f, 0.f, 0.f};
#pragma unroll
    for (int kc = 0; kc < 16; ++kc) {
        float4 v = *(const float4*)(src + (size_t)kc * 524288);
        s.x += v.x; s.y += v.y; s.z += v.z; s.w += v.w;
    }
    float mx = fmaxf(fmaxf(s.x, s.y), fmaxf(s.z, s.w));
#pragma unroll
    for (int d = 1; d < 64; d <<= 1) mx = fmaxf(mx, __shfl_xor(mx, d));
    float e0 = expf(s.x - mx), e1 = expf(s.y - mx), e2 = expf(s.z - mx), e3 = expf(s.w - mx);
    float sm = e0 + e1 + e2 + e3;
#pragma unroll
    for (int d = 1; d < 64; d <<= 1) sm += __shfl_xor(sm, d);
    float r = 1.f / sm;
    u16t* dst = pout + (size_t)row * 256 + l * 4;
    *(ushort4*)dst = make_ushort4(f2bf(e0 * r), f2bf(e1 * r), f2bf(e2 * r), f2bf(e3 * r));
}

// ---------------- K5: y = p . g  (one block per (b, 64-d slice)) -------------
// grid 1024 (XCD-chunked by batch), 512 thr = 8 waves; wave w -> n in [32w,+32).
// g tile (256 m x 64 d) staged ONCE, transposed: gl[d][m] stride 266 (odd-dword
// bank stride). p fragments read直接 from global (L2-hot). m-order identical
// to previous version -> bit-identical y.
__global__ void __launch_bounds__(512) k_pv(
    const u16t* __restrict__ pin, const u16t* __restrict__ g, u16t* __restrict__ y)
{
    __shared__ u16t gl[64 * 266];
    int phys = blockIdx.x;
    int blk = ((phys & 7) << 7) | (phys >> 3);   // one batch per XCD
    int b = blk >> 7, dt = blk & 127;
    int d0 = dt * 64;
    int t = threadIdx.x, w = t >> 6, l = t & 63, lr = l & 15, lg = l >> 4;
    int wn = w * 32;

    // ---- stage g once: thread = (m-pair, d-quarter); ushort2 writes
    {
        int mp = (t & 127) * 2;
        int dq = (t >> 7) * 16;
        const u16t* s0 = g + ((size_t)b * 256 + mp) * 8192 + d0 + dq;
        const u16t* s1 = s0 + 8192;
        s16x8 a0 = *(const s16x8*)s0;
        s16x8 a1 = *(const s16x8*)(s0 + 8);
        s16x8 b0 = *(const s16x8*)s1;
        s16x8 b1 = *(const s16x8*)(s1 + 8);
#pragma unroll
        for (int j = 0; j < 8; ++j) {
            *(ushort2*)(gl + (dq + j) * 266 + mp)     = make_ushort2((u16t)a0[j], (u16t)b0[j]);
            *(ushort2*)(gl + (dq + 8 + j) * 266 + mp) = make_ushort2((u16t)a1[j], (u16t)b1[j]);
        }
    }
    __syncthreads();

    f32x4 acc[2][4];
#pragma unroll
    for (int i = 0; i < 2; ++i)
#pragma unroll
        for (int j = 0; j < 4; ++j) acc[i][j] = (f32x4){0.f, 0.f, 0.f, 0.f};

#pragma unroll
    for (int mk = 0; mk < 8; ++mk) {
        s16x8 a[2];
#pragma unroll
        for (int rt = 0; rt < 2; ++rt)
            a[rt] = *(const s16x8*)(pin + ((size_t)b * 256 + wn + rt * 16 + lr) * 256
                                    + mk * 32 + lg * 8);
#pragma unroll
        for (int ct = 0; ct < 4; ++ct) {
            s16x8 bf = *(const s16x8*)(gl + (ct * 16 + lr) * 266 + mk * 32 + lg * 8);
#pragma unroll
            for (int rt = 0; rt < 2; ++rt)
                acc[rt][ct] = MFMA(a[rt], bf, acc[rt][ct]);
        }
    }
    u16t* yb = y + ((size_t)b * 256 + wn) * 8192 + d0;
#pragma unroll
    for (int rt = 0; rt < 2; ++rt)
#pragma unroll
        for (int r = 0; r < 4; ++r) {
            int nn = rt * 16 + lg * 4 + r;
#pragma unroll
            for (int ct = 0; ct < 4; ++ct)
                yb[(size_t)nn * 8192 + ct * 16 + lr] = f2bf(acc[rt][ct][r]);
        }
}

// ---------------- K6: w_y = y . w_w + w_b -> wy[b][n][o][s] + BN stats -------
__global__ void __launch_bounds__(128) k_wconv(
    const u16t* __restrict__ y, const u16t* __restrict__ wb, const float* __restrict__ w_b,
    u16t* __restrict__ wy, float* __restrict__ stats)
{
    __shared__ u16t yl[64 * 40];
    int blk = blockIdx.x;
    int b = blk >> 8, n = blk & 255;
    int t = threadIdx.x, w = t >> 6, l = t & 63, lr = l & 15, lg = l >> 4;
    int wo = w * 128;
    const u16t* wcv = wb + 163840;
    const u16t* yb = y + ((size_t)b * 256 + n) * 8192;
    f32x4 acc[4][8];
#pragma unroll
    for (int i = 0; i < 4; ++i)
#pragma unroll
        for (int j = 0; j < 8; ++j) acc[i][j] = (f32x4){0.f, 0.f, 0.f, 0.f};

    for (int kk = 0; kk < 4; ++kk) {
        __syncthreads();
        {   // stage 32c x 64s -> yl[s][40] (transposed, scalar writes)
            const u16t* src = yb + kk * 2048 + t * 16;
            int c = t >> 2, s0 = (t & 3) * 16;
            s16x8 v0 = *(const s16x8*)src;
            s16x8 v1 = *(const s16x8*)(src + 8);
#pragma unroll
            for (int j = 0; j < 8; ++j) {
                yl[(s0 + j) * 40 + c]     = (u16t)v0[j];
                yl[(s0 + 8 + j) * 40 + c] = (u16t)v1[j];
            }
        }
        __syncthreads();
        s16x8 a[4];
#pragma unroll
        for (int rt = 0; rt < 4; ++rt)
            a[rt] = *(const s16x8*)(yl + (rt * 16 + lr) * 40 + lg * 8);
#pragma unroll
        for (int ct = 0; ct < 8; ++ct) {
            int o = wo + ct * 16 + lr;
            s16x8 bf = *(const s16x8*)(wcv + o * 128 + kk * 32 + lg * 8);
#pragma unroll
            for (int rt = 0; rt < 4; ++rt)
                acc[rt][ct] = MFMA(a[rt], bf, acc[rt][ct]);
        }
    }
    // ---- epilogue: wy[b][n][o][s] (o-major token tile), ushort4 stores ------
    u16t* wyb = wy + ((size_t)b * 256 + n) * 16384;
    float s1[8], s2[8];
#pragma unroll
    for (int ct = 0; ct < 8; ++ct) { s1[ct] = 0.f; s2[ct] = 0.f; }
#pragma unroll
    for (int ct = 0; ct < 8; ++ct) {
        int o = wo + ct * 16 + lr;
        float bv = w_b[o];
#pragma unroll
        for (int rt = 0; rt < 4; ++rt) {
            float v0 = acc[rt][ct][0] + bv;
            float v1 = acc[rt][ct][1] + bv;
            float v2 = acc[rt][ct][2] + bv;
            float v3 = acc[rt][ct][3] + bv;
            s1[ct] += v0 + v1 + v2 + v3;
            s2[ct] += v0 * v0 + v1 * v1 + v2 * v2 + v3 * v3;
            *(ushort4*)(wyb + o * 64 + rt * 16 + lg * 4) =
                make_ushort4(f2bf(v0), f2bf(v1), f2bf(v2), f2bf(v3));
        }
    }
#pragma unroll
    for (int ct = 0; ct < 8; ++ct) {
        s1[ct] += __shfl_xor(s1[ct], 16); s1[ct] += __shfl_xor(s1[ct], 32);
        s2[ct] += __shfl_xor(s2[ct], 16); s2[ct] += __shfl_xor(s2[ct], 32);
        if (lg == 0) {
            int o = wo + ct * 16 + lr;
            atomicAdd(&stats[o], s1[ct]);
            atomicAdd(&stats[256 + o], s2[ct]);
        }
    }
}

// ---------------- K7: BN + residual, pure streaming (no LDS) -----------------
__global__ void __launch_bounds__(256) k_final(
    const u16t* __restrict__ wy, const float* __restrict__ x, const float* __restrict__ stats,
    const float* __restrict__ gamma, const float* __restrict__ beta, float* __restrict__ out)
{
    int blk = blockIdx.x;
    int ocg = blk & 15, pi = (blk >> 4) & 15, b = blk >> 8;
    int t = threadIdx.x;
    int pj = t & 15, ocs = t >> 4;
    int oc = ocg * 16 + ocs;
    int n = pi * 16 + pj;
    const float rcpN = 1.f / 131072.f;
    float mm = stats[oc] * rcpN;
    float vv = stats[256 + oc] * rcpN - mm * mm;
    float aa = gamma[oc] * rsqrtf(vv + 1e-5f);
    float cc = beta[oc] - mm * aa;
    const u16t* wyt = wy + (((size_t)b * 256 + n) * 256 + oc) * 64;
    size_t xbase = (((size_t)b * 256 + oc) * 128 + (size_t)pi * 8) * 128 + pj * 8;
#pragma unroll
    for (int u = 0; u < 8; ++u) {
        s16x8 v = *(const s16x8*)(wyt + u * 8);
        size_t xi = xbase + (size_t)u * 128;
        float4 x0 = *(const float4*)(x + xi);
        float4 x1 = *(const float4*)(x + xi + 4);
        float4 o0, o1;
        o0.x = bf2f((u16t)v[0]) * aa + cc + x0.x;
        o0.y = bf2f((u16t)v[1]) * aa + cc + x0.y;
        o0.z = bf2f((u16t)v[2]) * aa + cc + x0.z;
        o0.w = bf2f((u16t)v[3]) * aa + cc + x0.w;
        o1.x = bf2f((u16t)v[4]) * aa + cc + x1.x;
        o1.y = bf2f((u16t)v[5]) * aa + cc + x1.y;
        o1.z = bf2f((u16t)v[6]) * aa + cc + x1.z;
        o1.w = bf2f((u16t)v[7]) * aa + cc + x1.w;
        *(float4*)(out + xi) = o0;
        *(float4*)(out + xi + 4) = o1;
    }
}

// ---------------------------------------------------------------------------
extern "C" void kernel_launch(void* const* d_in, const int* in_sizes, int n_in,
                              void* d_out, int out_size, void* d_ws, size_t ws_size,
                              hipStream_t stream)
{
    (void)in_sizes; (void)n_in; (void)out_size;
    const float* x    = (const float*)d_in[0];
    const float* g_w  = (const float*)d_in[1];
    const float* g_b  = (const float*)d_in[2];
    const float* t_w  = (const float*)d_in[3];
    const float* t_b  = (const float*)d_in[4];
    const float* p_w  = (const float*)d_in[5];
    const float* p_b  = (const float*)d_in[6];
    const float* w_w  = (const float*)d_in[7];
    const float* w_b  = (const float*)d_in[8];
    const float* bn_g = (const float*)d_in[9];
    const float* bn_b = (const float*)d_in[10];

    const size_t G_OFF  = 0;
    const size_t FP_OFF = 33554432;
    const size_t WY_OFF = 33554432;          // aliases FP (dead after softmax)
    const size_t P_OFF  = 100663296;
    const size_t ST_OFF = 101711872;
    const size_t WB_OFF = 101713920;
    const size_t NEEDED = 102107136;
    if (ws_size < NEEDED) return;

    char* ws = (char*)d_ws;
    u16t*  g_buf = (u16t*)(ws + G_OFF);
    float* fp    = (float*)(ws + FP_OFF);
    u16t*  wy    = (u16t*)(ws + WY_OFF);
    u16t*  p_buf = (u16t*)(ws + P_OFF);
    float* stats = (float*)(ws + ST_OFF);
    u16t*  wb    = (u16t*)(ws + WB_OFF);

    float* th_g = (float*)d_out;             // theta fp32 (16.78M floats)
    float* ph_g = th_g + 16777216;           // phi fp32
    u16t*  y_buf = (u16t*)d_out;             // y bf16 (reuses d_out after QK)

    k_prep<<<128, 256, 0, stream>>>(g_w, t_w, p_w, w_w, wb, stats);
    k_proj<<<2048, 512, 0, stream>>>(x, wb, t_b, p_b, g_b, th_g, ph_g, g_buf);
    k_qk<<<512, 256, 0, stream>>>(th_g, ph_g, fp);
    k_softmax<<<512, 256, 0, stream>>>(fp, p_buf);
    k_pv<<<1024, 512, 0, stream>>>(p_buf, g_buf, y_buf);
    k_wconv<<<2048, 128, 0, stream>>>(y_buf, wb, w_b, wy, stats);
    k_final<<<2048, 256, 0, stream>>>(wy, x, stats, bn_g, bn_b, (float*)d_out);
}